// Round 11
// baseline (325.415 us; speedup 1.0000x reference)
//
#include <hip/hip_runtime.h>
#include <math.h>

#define B_ 32
#define D_ 512
#define T_ 256
#define NH_ 8
#define DK_ 64
#define ML_ 25

typedef unsigned short ushort_t;
using short8 = __attribute__((ext_vector_type(8))) short;
using f32x4  = __attribute__((ext_vector_type(4))) float;

__device__ __forceinline__ ushort_t f2bf(float f) {
    unsigned u = __float_as_uint(f);
    unsigned r = (u + 0x7fffu + ((u >> 16) & 1u)) >> 16;
    return (ushort_t)r;
}
__device__ __forceinline__ float bf2f(ushort_t h) {
    return __uint_as_float(((unsigned)h) << 16);
}
__device__ __forceinline__ void gl16(const void* g, void* l) {
    __builtin_amdgcn_global_load_lds((const __attribute__((address_space(1))) void*)g,
                                     (__attribute__((address_space(3))) void*)l, 16, 0, 0);
}
#define ZERO4(v) { (v)[0]=0.f; (v)[1]=0.f; (v)[2]=0.f; (v)[3]=0.f; }

// stats layout: [5 slots][8192 rows][2] (sum, sumsq) then u[4608], v[4608]
#define STATS_F (5 * 8192 * 2)
#define UV_F    4608

// ---------------- zero stats+uv (ws not re-poisoned between replays) ----------------
__global__ __launch_bounds__(256) void zero_kernel(float* __restrict__ z) {
    int idx = blockIdx.x * 256 + threadIdx.x;
    if (idx < (STATS_F + 2 * UV_F + 3) / 4) {
        float4 zz = {0.f, 0.f, 0.f, 0.f};
        ((float4*)z)[idx] = zz;
    }
}

// ---------------- u[c]=sum_k s[k]W[k][c], v[c]=sum_k b[k]W[k][c] (9 mats, k-split 4) ----------------
__global__ __launch_bounds__(256) void uv_kernel(const float* __restrict__ Wq,
                                                 const float* __restrict__ Wk,
                                                 const float* __restrict__ Wv,
                                                 const float* __restrict__ W1,
                                                 const float* __restrict__ fc0,
                                                 const float* __restrict__ ln1_s, const float* __restrict__ ln1_b,
                                                 const float* __restrict__ ln2_s, const float* __restrict__ ln2_b,
                                                 const float* __restrict__ lnf_s, const float* __restrict__ lnf_b,
                                                 float* __restrict__ u, float* __restrict__ v) {
    int idx = blockIdx.x;
    int k0 = blockIdx.y * 128;
    const float* W; const float* s; const float* b; int off;
    if (idx < 6) {
        int l = idx / 3, w = idx % 3;
        W = (w == 0 ? Wq : (w == 1 ? Wk : Wv)) + (size_t)l * D_ * D_;
        s = ln1_s + l * D_; b = ln1_b + l * D_;
        off = l * 1536 + w * 512;
    } else if (idx < 8) {
        int l = idx - 6;
        W = W1 + (size_t)l * D_ * D_;
        s = ln2_s + l * D_; b = ln2_b + l * D_;
        off = 3072 + l * 512;
    } else {
        W = fc0; s = lnf_s; b = lnf_b; off = 4096;
    }
    int tid = threadIdx.x;
#pragma unroll
    for (int pass = 0; pass < 2; pass++) {
        int c = tid + pass * 256;
        float ua = 0.f, va = 0.f;
        for (int k = k0; k < k0 + 128; k++) {
            float w = W[(size_t)k * D_ + c];
            ua += s[k] * w; va += b[k] * w;
        }
        atomicAdd(&u[off + c], ua);
        atomicAdd(&v[off + c], va);
    }
}

// ---------------- prep: enc + bf16 copy + row stats (slot 0) ----------------
__global__ __launch_bounds__(256) void prep_kernel(const float* __restrict__ x,
                                                   const int* __restrict__ epos,
                                                   const float* __restrict__ pos,
                                                   float* __restrict__ enc,
                                                   ushort_t* __restrict__ hi,
                                                   float* __restrict__ st) {
    __shared__ float ld[64][65];
    int tt = blockIdx.x, ct = blockIdx.y, b = blockIdx.z;
    int t0 = tt * 64, c0 = ct * 64;
    int tid = threadIdx.x;
    int r = tid >> 4, c4 = (tid & 15) << 2;
#pragma unroll
    for (int p = 0; p < 4; p++) {
        int row = p * 16 + r;
        float4 v = *(const float4*)(x + ((size_t)(b * D_ + c0 + row) * T_ + t0) + c4);
        ld[row][c4 + 0] = v.x; ld[row][c4 + 1] = v.y; ld[row][c4 + 2] = v.z; ld[row][c4 + 3] = v.w;
    }
    __syncthreads();
#pragma unroll
    for (int p = 0; p < 4; p++) {
        int tr = p * 16 + r;
        int ep = epos[t0 + tr];
        float4 pv = *(const float4*)(pos + (size_t)ep * D_ + c0 + c4);
        float4 o;
        o.x = ld[c4 + 0][tr] * 22.627417f + pv.x;
        o.y = ld[c4 + 1][tr] * 22.627417f + pv.y;
        o.z = ld[c4 + 2][tr] * 22.627417f + pv.z;
        o.w = ld[c4 + 3][tr] * 22.627417f + pv.w;
        size_t row = (size_t)(b * T_ + t0 + tr);
        *(float4*)(enc + row * D_ + c0 + c4) = o;
        *(ushort4*)(hi + row * D_ + c0 + c4) = make_ushort4(f2bf(o.x), f2bf(o.y), f2bf(o.z), f2bf(o.w));
        float sx = o.x + o.y + o.z + o.w;
        float sq = o.x*o.x + o.y*o.y + o.z*o.z + o.w*o.w;
        sx += __shfl_xor(sx, 1); sq += __shfl_xor(sq, 1);
        sx += __shfl_xor(sx, 2); sq += __shfl_xor(sq, 2);
        sx += __shfl_xor(sx, 4); sq += __shfl_xor(sq, 4);
        sx += __shfl_xor(sx, 8); sq += __shfl_xor(sq, 8);
        if ((tid & 15) == 0) {
            atomicAdd(&st[2 * row], sx);
            atomicAdd(&st[2 * row + 1], sq);
        }
    }
}

// ---------------- weight convert: WT[n][k] = bf16(s[k]*W[k][n]); fc0 also lo ----------------
__global__ __launch_bounds__(256) void convert_w_kernel(const float* __restrict__ Wq,
                                                        const float* __restrict__ Wk,
                                                        const float* __restrict__ Wv,
                                                        const float* __restrict__ Wo,
                                                        const float* __restrict__ W1,
                                                        const float* __restrict__ W2,
                                                        const float* __restrict__ fc0,
                                                        const float* __restrict__ ln1_s,
                                                        const float* __restrict__ ln2_s,
                                                        const float* __restrict__ lnf_s,
                                                        ushort_t* __restrict__ wt) {
    __shared__ float ld[64][65];
    int m = blockIdx.x >> 6;
    int tile = blockIdx.x & 63;
    int tn = tile >> 3, tk = tile & 7;
    int n0 = tn * 64, k0 = tk * 64;
    const float* src;
    const float* sArr = nullptr;
    if (m < 12) {
        int l = m / 6, w = m % 6;
        const float* bases[6] = {Wq, Wk, Wv, Wo, W1, W2};
        src = bases[w] + (size_t)l * D_ * D_;
        if (w < 3) sArr = ln1_s + l * D_;
        else if (w == 4) sArr = ln2_s + l * D_;
    } else {
        src = fc0;
        sArr = lnf_s;
    }
    int tid = threadIdx.x;
    int r = tid >> 4, c4 = (tid & 15) << 2;
#pragma unroll
    for (int p = 0; p < 4; p++) {
        int row = p * 16 + r;
        float4 v = *(const float4*)(src + (size_t)(k0 + row) * D_ + n0 + c4);
        ld[row][c4 + 0] = v.x; ld[row][c4 + 1] = v.y; ld[row][c4 + 2] = v.z; ld[row][c4 + 3] = v.w;
    }
    float sv[4];
#pragma unroll
    for (int i = 0; i < 4; i++) sv[i] = sArr ? sArr[k0 + c4 + i] : 1.f;
    __syncthreads();
    ushort_t* dsth = wt + (size_t)m * D_ * D_;
    ushort_t* dstl = wt + (size_t)13 * D_ * D_;
#pragma unroll
    for (int p = 0; p < 4; p++) {
        int n = p * 16 + r;
        int kc = c4;
        ushort_t h[4], lo[4];
#pragma unroll
        for (int i = 0; i < 4; i++) {
            float f = ld[kc + i][n] * sv[i];
            h[i] = f2bf(f);
            lo[i] = f2bf(f - bf2f(h[i]));
        }
        *(ushort4*)(dsth + (size_t)(n0 + n) * D_ + k0 + kc) = make_ushort4(h[0], h[1], h[2], h[3]);
        if (m == 12)
            *(ushort4*)(dstl + (size_t)(n0 + n) * D_ + k0 + kc) = make_ushort4(lo[0], lo[1], lo[2], lo[3]);
    }
}

// ---------------- MFMA GEMM: tile 128x64, 3-buffer counted-vmcnt (round-8 core) ----------------
// EPI 2: producer: res-add -> enc f32 + bf16 copy + stats atomics
// EPI 6: producer final: res-add -> bf16 hi + lo + stats atomics (no f32 out)
// EPI 3: consumer LN-fold + relu -> bf16
// EPI 4: consumer LN-fold -> f32 (fc0)
template<int EPI>
__global__ __launch_bounds__(256) void gemm_kernel(const ushort_t* __restrict__ A0,
                                                   const ushort_t* __restrict__ A1,
                                                   const ushort_t* __restrict__ B0,
                                                   const ushort_t* __restrict__ B1,
                                                   int nseg, int nbn,
                                                   const float* __restrict__ bias,
                                                   const float* __restrict__ res,
                                                   float* __restrict__ outF,
                                                   ushort_t* __restrict__ outB,
                                                   ushort_t* __restrict__ outB2,
                                                   const float* __restrict__ stIn,
                                                   const float* __restrict__ u,
                                                   const float* __restrict__ v,
                                                   float* __restrict__ stOut) {
    __shared__ ushort_t As[3][128 * 64];
    __shared__ ushort_t Bs[3][64 * 64];
    int tid = threadIdx.x;
    int g = blockIdx.x;
    int per = gridDim.x >> 3;
    int lin = (g & 7) * per + (g >> 3);
    int bm = lin / nbn, bn = lin % nbn;

    int lane = tid & 63;
    int wid = tid >> 6;
    int wm = wid >> 1, wn = wid & 1;
    int xr = (lane & 7) << 3;

    f32x4 acc[4][2];
#pragma unroll
    for (int i = 0; i < 4; i++)
#pragma unroll
        for (int j = 0; j < 2; j++) ZERO4(acc[i][j]);

    int nt = nseg * 8;

#define STAGE(kt, buf)                                                                  \
    {                                                                                   \
        int seg_ = (kt) >> 3;                                                           \
        int k0_ = ((kt) & 7) * 64;                                                      \
        const ushort_t* Asg = seg_ == 0 ? A0 : A1;                                      \
        const ushort_t* Bsg = seg_ == 0 ? B0 : B1;                                      \
        _Pragma("unroll")                                                               \
        for (int it = 0; it < 4; it++) {                                                \
            int uu = tid + it * 256;                                                    \
            int row_ = uu >> 3;                                                         \
            int kb_ = (((uu & 7) ^ (row_ & 7)) << 3);                                   \
            gl16(Asg + (size_t)(bm * 128 + row_) * 512 + k0_ + kb_, &As[buf][uu * 8]);  \
        }                                                                               \
        _Pragma("unroll")                                                               \
        for (int it = 0; it < 2; it++) {                                                \
            int uu = tid + it * 256;                                                    \
            int row_ = uu >> 3;                                                         \
            int kb_ = (((uu & 7) ^ (row_ & 7)) << 3);                                   \
            gl16(Bsg + (size_t)(bn * 64 + row_) * 512 + k0_ + kb_, &Bs[buf][uu * 8]);   \
        }                                                                               \
    }

#define COMPUTE(bufc)                                                                        \
    {                                                                                        \
        _Pragma("unroll")                                                                    \
        for (int kc = 0; kc < 2; kc++) {                                                     \
            short8 a[4], b[2];                                                               \
            int koff = (kc * 32 + ((lane >> 4) << 3)) ^ xr;                                  \
            _Pragma("unroll")                                                                \
            for (int i = 0; i < 4; i++)                                                      \
                a[i] = *(const short8*)&As[bufc][(wm * 64 + i * 16 + (lane & 15)) * 64 + koff]; \
            _Pragma("unroll")                                                                \
            for (int j = 0; j < 2; j++)                                                      \
                b[j] = *(const short8*)&Bs[bufc][(wn * 32 + j * 16 + (lane & 15)) * 64 + koff]; \
            _Pragma("unroll")                                                                \
            for (int i = 0; i < 4; i++)                                                      \
                _Pragma("unroll")                                                            \
                for (int j = 0; j < 2; j++)                                                  \
                    acc[i][j] = __builtin_amdgcn_mfma_f32_16x16x32_bf16(a[i], b[j], acc[i][j], 0, 0, 0); \
        }                                                                                    \
    }

    STAGE(0, 0);
    if (nt > 1) STAGE(1, 1);
    asm volatile("s_waitcnt vmcnt(6)" ::: "memory");
    __builtin_amdgcn_s_barrier();

    int cur = 0;
    for (int t = 0; t < nt; t++) {
        if (t + 2 < nt) STAGE(t + 2, (cur + 2 >= 3 ? cur - 1 : cur + 2));   // (cur+2)%3
        COMPUTE(cur);
        if (t + 2 < nt) {
            asm volatile("s_waitcnt vmcnt(6)" ::: "memory");
        } else if (t + 1 < nt) {
            asm volatile("s_waitcnt vmcnt(0)" ::: "memory");
        }
        __builtin_amdgcn_s_barrier();
        cur = (cur == 2) ? 0 : cur + 1;
    }
#undef STAGE
#undef COMPUTE

    if (EPI == 2 || EPI == 6) {
        // producer: res-add, bf16 copy (+lo), per-row stats
#pragma unroll
        for (int i = 0; i < 4; i++) {
#pragma unroll
            for (int jj = 0; jj < 4; jj++) {
                int row = bm * 128 + wm * 64 + i * 16 + ((lane >> 4) << 2) + jj;
                float sx = 0.f, sq = 0.f;
#pragma unroll
                for (int j = 0; j < 2; j++) {
                    int col = bn * 64 + wn * 32 + j * 16 + (lane & 15);
                    size_t idx = (size_t)row * 512 + col;
                    float val = acc[i][j][jj] + bias[col] + res[idx];
                    if (EPI == 2) outF[idx] = val;
                    ushort_t hv = f2bf(val);
                    outB[idx] = hv;
                    if (EPI == 6) outB2[idx] = f2bf(val - bf2f(hv));
                    sx += val; sq += val * val;
                }
                sx += __shfl_xor(sx, 1); sq += __shfl_xor(sq, 1);
                sx += __shfl_xor(sx, 2); sq += __shfl_xor(sq, 2);
                sx += __shfl_xor(sx, 4); sq += __shfl_xor(sq, 4);
                sx += __shfl_xor(sx, 8); sq += __shfl_xor(sq, 8);
                if ((lane & 15) == 0) {
                    atomicAdd(&stOut[2 * row], sx);
                    atomicAdd(&stOut[2 * row + 1], sq);
                }
            }
        }
    } else {
        // consumer: LN-fold epilogue
#pragma unroll
        for (int i = 0; i < 4; i++) {
#pragma unroll
            for (int j = 0; j < 2; j++) {
                int col = bn * 64 + wn * 32 + j * 16 + (lane & 15);
                float bc = bias[col];
                float uc = u[col];
                float vc = v[col];
#pragma unroll
                for (int jj = 0; jj < 4; jj++) {
                    int row = bm * 128 + wm * 64 + i * 16 + ((lane >> 4) << 2) + jj;
                    float s0 = stIn[2 * row], s1 = stIn[2 * row + 1];
                    float mu = s0 * (1.f / 512.f);
                    float rs = rsqrtf(s1 * (1.f / 512.f) - mu * mu + 1e-5f);
                    float val = rs * (acc[i][j][jj] - mu * uc) + vc + bc;
                    size_t idx = (size_t)row * 512 + col;
                    if (EPI == 3) outB[idx] = f2bf(fmaxf(val, 0.f));
                    else outF[idx] = val;
                }
            }
        }
    }
}

// ---------------- wide MFMA GEMM for fused QKV (LN-fold consumer): tile 128x128, N=1536 ----------------
__global__ __launch_bounds__(256) void gemm_qkv_kernel(const ushort_t* __restrict__ A,
                                                       const ushort_t* __restrict__ W,
                                                       const float* __restrict__ bq,
                                                       const float* __restrict__ bk,
                                                       const float* __restrict__ bv,
                                                       const float* __restrict__ stIn,
                                                       const float* __restrict__ u,
                                                       const float* __restrict__ v,
                                                       ushort_t* __restrict__ outB) {
    __shared__ ushort_t As[2][128 * 64];
    __shared__ ushort_t Bs[2][128 * 64];
    int tid = threadIdx.x;
    int g = blockIdx.x;
    int per = gridDim.x >> 3;
    int lin = (g & 7) * per + (g >> 3);
    int bm = lin / 12, bn = lin % 12;

    int lane = tid & 63;
    int wid = tid >> 6;
    int wm = wid >> 1, wn = wid & 1;
    int xr = (lane & 7) << 3;

    f32x4 acc[4][4];
#pragma unroll
    for (int i = 0; i < 4; i++)
#pragma unroll
        for (int j = 0; j < 4; j++) ZERO4(acc[i][j]);

#define QSTAGE(kt, buf)                                                                 \
    {                                                                                   \
        int k0_ = (kt) * 64;                                                            \
        _Pragma("unroll")                                                               \
        for (int it = 0; it < 4; it++) {                                                \
            int uu = tid + it * 256;                                                    \
            int row_ = uu >> 3;                                                         \
            int kb_ = (((uu & 7) ^ (row_ & 7)) << 3);                                   \
            gl16(A + (size_t)(bm * 128 + row_) * 512 + k0_ + kb_, &As[buf][uu * 8]);    \
            gl16(W + (size_t)(bn * 128 + row_) * 512 + k0_ + kb_, &Bs[buf][uu * 8]);    \
        }                                                                               \
    }

    QSTAGE(0, 0);
    asm volatile("s_waitcnt vmcnt(0)" ::: "memory");
    __builtin_amdgcn_s_barrier();

    int buf = 0;
    for (int t = 0; t < 8; t++) {
        if (t + 1 < 8) QSTAGE(t + 1, buf ^ 1);
#pragma unroll
        for (int kc = 0; kc < 2; kc++) {
            short8 a[4], b[4];
            int koff = (kc * 32 + ((lane >> 4) << 3)) ^ xr;
#pragma unroll
            for (int i = 0; i < 4; i++)
                a[i] = *(const short8*)&As[buf][(wm * 64 + i * 16 + (lane & 15)) * 64 + koff];
#pragma unroll
            for (int j = 0; j < 4; j++)
                b[j] = *(const short8*)&Bs[buf][(wn * 64 + j * 16 + (lane & 15)) * 64 + koff];
#pragma unroll
            for (int i = 0; i < 4; i++)
#pragma unroll
                for (int j = 0; j < 4; j++)
                    acc[i][j] = __builtin_amdgcn_mfma_f32_16x16x32_bf16(a[i], b[j], acc[i][j], 0, 0, 0);
        }
        if (t + 1 < 8) asm volatile("s_waitcnt vmcnt(0)" ::: "memory");
        __builtin_amdgcn_s_barrier();
        buf ^= 1;
    }
#undef QSTAGE

#pragma unroll
    for (int i = 0; i < 4; i++) {
#pragma unroll
        for (int j = 0; j < 4; j++) {
            int r0 = bm * 128 + wm * 64 + i * 16 + ((lane >> 4) << 2);
            int col = bn * 128 + wn * 64 + j * 16 + (lane & 15);
            int seg = col >> 9;
            int ccol = col & 511;
            const float* bp = (seg == 0) ? bq : (seg == 1 ? bk : bv);
            float bc = bp[ccol];
            float uc = u[col];
            float vc = v[col];
#pragma unroll
            for (int jj = 0; jj < 4; jj++) {
                int row = r0 + jj;
                float s0 = stIn[2 * row], s1 = stIn[2 * row + 1];
                float mu = s0 * (1.f / 512.f);
                float rs = rsqrtf(s1 * (1.f / 512.f) - mu * mu + 1e-5f);
                float val = rs * (acc[i][j][jj] - mu * uc) + vc + bc;
                if (seg < 2) {
                    outB[(size_t)seg * 4194304 + (size_t)row * 512 + ccol] = f2bf(val);
                } else {
                    int bb2 = row >> 8, t2 = row & 255;
                    outB[(size_t)2 * 4194304 +
                         ((size_t)(bb2 * 8 + (ccol >> 6)) * 64 + (ccol & 63)) * 256 + t2] = f2bf(val);
                }
            }
        }
    }
}

// ---------------- fused attention: block = (64 q-rows, bh). QK^T -> softmax -> PV ----------------
__global__ __launch_bounds__(256) void attn_fused_kernel(const ushort_t* __restrict__ q,
                                                         const ushort_t* __restrict__ k,
                                                         const ushort_t* __restrict__ vt,
                                                         ushort_t* __restrict__ ao) {
    __shared__ ushort_t KVs[256 * 64];
    __shared__ ushort_t Ps[64 * 256];
    int tid = threadIdx.x;
    int lane = tid & 63;
    int wid = tid >> 6;
    int m0 = blockIdx.x * 64;
    int bh = blockIdx.y;
    int b = bh >> 3, h = bh & 7;
    int xr = (lane & 7) << 3;

#pragma unroll
    for (int it = 0; it < 8; it++) {
        int uu = tid + it * 256;
        int row = uu >> 3;
        int gx = ((uu & 7) ^ (row & 7)) << 3;
        gl16(k + (size_t)(b * T_ + row) * D_ + h * DK_ + gx, &KVs[uu * 8]);
    }
    short8 qa0, qa1;
    {
        int qrow = m0 + wid * 16 + (lane & 15);
        const ushort_t* qp = q + (size_t)(b * T_ + qrow) * D_ + h * DK_ + ((lane >> 4) << 3);
        qa0 = *(const short8*)(qp);
        qa1 = *(const short8*)(qp + 32);
    }
    f32x4 acc[16];
#pragma unroll
    for (int j = 0; j < 16; j++) ZERO4(acc[j]);
    asm volatile("s_waitcnt vmcnt(0)" ::: "memory");
    __syncthreads();

#pragma unroll
    for (int j = 0; j < 16; j++) {
        int krow = j * 16 + (lane & 15);
        short8 b0 = *(const short8*)&KVs[krow * 64 + ((((lane >> 4) << 3)) ^ xr)];
        short8 b1 = *(const short8*)&KVs[krow * 64 + ((32 + ((lane >> 4) << 3)) ^ xr)];
        acc[j] = __builtin_amdgcn_mfma_f32_16x16x32_bf16(qa0, b0, acc[j], 0, 0, 0);
        acc[j] = __builtin_amdgcn_mfma_f32_16x16x32_bf16(qa1, b1, acc[j], 0, 0, 0);
    }
    __syncthreads();

#pragma unroll
    for (int it = 0; it < 8; it++) {
        int uu = tid + it * 256;
        int row = uu >> 5;
        int gx = ((uu & 31) ^ (row & 7)) << 3;
        gl16(vt + ((size_t)bh * DK_ + row) * T_ + gx, &KVs[uu * 8]);
    }

    const float C = 0.125f * 1.44269504f;
#pragma unroll
    for (int jj = 0; jj < 4; jj++) {
        float mx = -1e30f;
#pragma unroll
        for (int j = 0; j < 16; j++) mx = fmaxf(mx, acc[j][jj]);
#pragma unroll
        for (int msk = 1; msk < 16; msk <<= 1) mx = fmaxf(mx, __shfl_xor(mx, msk));
        float sm = 0.f;
#pragma unroll
        for (int j = 0; j < 16; j++) {
            float e = __builtin_amdgcn_exp2f((acc[j][jj] - mx) * C);
            acc[j][jj] = e;
            sm += e;
        }
#pragma unroll
        for (int msk = 1; msk < 16; msk <<= 1) sm += __shfl_xor(sm, msk);
        float inv = 1.f / sm;
#pragma unroll
        for (int j = 0; j < 16; j++) acc[j][jj] *= inv;
    }
#pragma unroll
    for (int j = 0; j < 16; j++) {
#pragma unroll
        for (int jj = 0; jj < 4; jj++) {
            int row = wid * 16 + ((lane >> 4) << 2) + jj;
            int col = j * 16 + (lane & 15);
            Ps[row * 256 + (col ^ ((row & 7) << 3))] = f2bf(acc[j][jj]);
        }
    }
    asm volatile("s_waitcnt vmcnt(0)" ::: "memory");
    __syncthreads();

    int wm = wid >> 1, wn = wid & 1;
    f32x4 acc2[2][2];
#pragma unroll
    for (int i = 0; i < 2; i++)
#pragma unroll
        for (int j = 0; j < 2; j++) ZERO4(acc2[i][j]);
#pragma unroll
    for (int kc = 0; kc < 8; kc++) {
        int off = (kc * 32 + ((lane >> 4) << 3)) ^ xr;
        short8 a0 = *(const short8*)&Ps[(wm * 32 + (lane & 15)) * 256 + off];
        short8 a1 = *(const short8*)&Ps[(wm * 32 + 16 + (lane & 15)) * 256 + off];
        short8 b0 = *(const short8*)&KVs[(wn * 32 + (lane & 15)) * 256 + off];
        short8 b1 = *(const short8*)&KVs[(wn * 32 + 16 + (lane & 15)) * 256 + off];
        acc2[0][0] = __builtin_amdgcn_mfma_f32_16x16x32_bf16(a0, b0, acc2[0][0], 0, 0, 0);
        acc2[0][1] = __builtin_amdgcn_mfma_f32_16x16x32_bf16(a0, b1, acc2[0][1], 0, 0, 0);
        acc2[1][0] = __builtin_amdgcn_mfma_f32_16x16x32_bf16(a1, b0, acc2[1][0], 0, 0, 0);
        acc2[1][1] = __builtin_amdgcn_mfma_f32_16x16x32_bf16(a1, b1, acc2[1][1], 0, 0, 0);
    }
#pragma unroll
    for (int i = 0; i < 2; i++)
#pragma unroll
        for (int j = 0; j < 2; j++)
#pragma unroll
            for (int jj = 0; jj < 4; jj++)
                ao[(size_t)(b * T_ + m0 + wm * 32 + i * 16 + ((lane >> 4) << 2) + jj) * D_ +
                   h * DK_ + wn * 32 + j * 16 + (lane & 15)] = f2bf(acc2[i][j][jj]);
}

// ---------------- PVAM scores ----------------
__global__ __launch_bounds__(256) void scores_kernel(const float* __restrict__ wf,
                                                     const int* __restrict__ gpos,
                                                     const float* __restrict__ emb,
                                                     const float* __restrict__ w1,
                                                     float* __restrict__ scores) {
    __shared__ float wpL[5][512];
    __shared__ float w1m2[512];
    const float K2 = 2.885390082f;  // 2*log2(e)
    int tid = threadIdx.x;
    int b = blockIdx.y;
    int mg = blockIdx.z * 5;
    int t = blockIdx.x * 32 + (tid >> 3);
    int cg = tid & 7;
    for (int idx = tid; idx < 5 * 128; idx += 256) {
        int m = idx >> 7, w4 = idx & 127;
        float4 v = *(const float4*)(emb + (size_t)gpos[mg + m] * D_ + (w4 << 2));
        v.x *= K2; v.y *= K2; v.z *= K2; v.w *= K2;
        *(float4*)&wpL[m][w4 << 2] = v;
    }
    if (tid < 128) {
        float4 v = *(const float4*)(w1 + (tid << 2));
        v.x *= -2.f; v.y *= -2.f; v.z *= -2.f; v.w *= -2.f;
        *(float4*)&w1m2[tid << 2] = v;
    }
    float4 wfs[16];
    float W1S = 0.f;
    const float* wfr = wf + (size_t)(b * T_ + t) * D_ + (cg << 2);
#pragma unroll
    for (int j = 0; j < 16; j++) {
        float4 v = *(const float4*)(wfr + (j << 5));
        wfs[j].x = v.x * K2; wfs[j].y = v.y * K2; wfs[j].z = v.z * K2; wfs[j].w = v.w * K2;
        float4 wv = *(const float4*)(w1 + (cg << 2) + (j << 5));
        W1S += wv.x + wv.y + wv.z + wv.w;
    }
    __syncthreads();
    float s[5] = {W1S, W1S, W1S, W1S, W1S};
#pragma unroll
    for (int j = 0; j < 16; j++) {
        float4 w14 = *(const float4*)&w1m2[(cg << 2) + (j << 5)];
#pragma unroll
        for (int m = 0; m < 5; m++) {
            float4 wp4 = *(const float4*)&wpL[m][(cg << 2) + (j << 5)];
            s[m] += w14.x * __builtin_amdgcn_rcpf(__builtin_amdgcn_exp2f(wfs[j].x + wp4.x) + 1.f);
            s[m] += w14.y * __builtin_amdgcn_rcpf(__builtin_amdgcn_exp2f(wfs[j].y + wp4.y) + 1.f);
            s[m] += w14.z * __builtin_amdgcn_rcpf(__builtin_amdgcn_exp2f(wfs[j].z + wp4.z) + 1.f);
            s[m] += w14.w * __builtin_amdgcn_rcpf(__builtin_amdgcn_exp2f(wfs[j].w + wp4.w) + 1.f);
        }
    }
#pragma unroll
    for (int m = 0; m < 5; m++) {
        s[m] += __shfl_xor(s[m], 1);
        s[m] += __shfl_xor(s[m], 2);
        s[m] += __shfl_xor(s[m], 4);
    }
    if (cg == 0) {
#pragma unroll
        for (int m = 0; m < 5; m++)
            scores[((size_t)b * ML_ + mg + m) * T_ + t] = s[m];
    }
}

// weighted sum with fused softmax
__global__ __launch_bounds__(256) void wsum_kernel(const float* __restrict__ scores,
                                                   const float* __restrict__ wf,
                                                   float* __restrict__ out) {
    __shared__ float at[T_][8];
    __shared__ float redmax[4][8];
    __shared__ float redsum[4][8];
    int tid = threadIdx.x;
    int lane = tid & 63, wv = tid >> 6;
    int b = blockIdx.y, m0 = blockIdx.x * 5;
    float s[5];
#pragma unroll
    for (int q = 0; q < 5; q++)
        s[q] = scores[((size_t)b * ML_ + m0 + q) * T_ + tid];
#pragma unroll
    for (int q = 0; q < 5; q++) {
        float mx = s[q];
        for (int o = 32; o; o >>= 1) mx = fmaxf(mx, __shfl_xor(mx, o));
        if (lane == 0) redmax[wv][q] = mx;
    }
    __syncthreads();
    float e[5];
#pragma unroll
    for (int q = 0; q < 5; q++) {
        float m = fmaxf(fmaxf(redmax[0][q], redmax[1][q]), fmaxf(redmax[2][q], redmax[3][q]));
        e[q] = __expf(s[q] - m);
        float sm = e[q];
        for (int o = 32; o; o >>= 1) sm += __shfl_xor(sm, o);
        if (lane == 0) redsum[wv][q] = sm;
    }
    __syncthreads();
#pragma unroll
    for (int q = 0; q < 5; q++) {
        float sm = redsum[0][q] + redsum[1][q] + redsum[2][q] + redsum[3][q];
        at[tid][q] = e[q] / sm;
    }
    __syncthreads();
    int c0 = tid << 1;
    const float* wfb = wf + (size_t)b * T_ * D_ + c0;
    float acc[5][2] = {};
    for (int t = 0; t < T_; t++) {
        float2 v = *(const float2*)(wfb + (size_t)t * D_);
        float4 a4 = *(const float4*)&at[t][0];
        float a5 = at[t][4];
        acc[0][0] += a4.x * v.x; acc[0][1] += a4.x * v.y;
        acc[1][0] += a4.y * v.x; acc[1][1] += a4.y * v.y;
        acc[2][0] += a4.z * v.x; acc[2][1] += a4.z * v.y;
        acc[3][0] += a4.w * v.x; acc[3][1] += a4.w * v.y;
        acc[4][0] += a5 * v.x;   acc[4][1] += a5 * v.y;
    }
#pragma unroll
    for (int q = 0; q < 5; q++) {
        float2 o;
        o.x = acc[q][0]; o.y = acc[q][1];
        *(float2*)(out + ((size_t)b * ML_ + m0 + q) * D_ + c0) = o;
    }
}

extern "C" void kernel_launch(void* const* d_in, const int* in_sizes, int n_in,
                              void* d_out, int out_size, void* d_ws, size_t ws_size,
                              hipStream_t stream) {
    (void)in_sizes; (void)n_in; (void)out_size; (void)ws_size;
    const float* x        = (const float*)d_in[0];
    const int*   epos     = (const int*)d_in[1];
    const int*   gpos     = (const int*)d_in[2];
    const float* pos_tab  = (const float*)d_in[3];
    const float* ln1_s    = (const float*)d_in[4];
    const float* ln1_b    = (const float*)d_in[5];
    const float* Wq       = (const float*)d_in[6];
    const float* bq       = (const float*)d_in[7];
    const float* Wk       = (const float*)d_in[8];
    const float* bk       = (const float*)d_in[9];
    const float* Wv       = (const float*)d_in[10];
    const float* bv       = (const float*)d_in[11];
    const float* Wo       = (const float*)d_in[12];
    const float* bo       = (const float*)d_in[13];
    const float* ln2_s    = (const float*)d_in[14];
    const float* ln2_b    = (const float*)d_in[15];
    const float* W1       = (const float*)d_in[16];
    const float* b1       = (const float*)d_in[17];
    const float* W2       = (const float*)d_in[18];
    const float* b2       = (const float*)d_in[19];
    const float* lnf_s    = (const float*)d_in[20];
    const float* lnf_b    = (const float*)d_in[21];
    const float* fc0_w    = (const float*)d_in[22];
    const float* fc0_b    = (const float*)d_in[23];
    const float* emb      = (const float*)d_in[24];
    const float* fc1_w    = (const float*)d_in[25];

    char* ws = (char*)d_ws;
    float*    enc = (float*)(ws);                       // 16.78 MB
    ushort_t* hi  = (ushort_t*)(ws + 16777216);         // 8.39 MB (raw enc bf16)
    ushort_t* qb  = (ushort_t*)(ws + 25165824);         // q
    ushort_t* kb  = (ushort_t*)(ws + 33554432);         // k (lo / scb overlay later)
    ushort_t* lo  = (ushort_t*)(ws + 33554432);
    float*    scb = (float*)(ws + 33554432);
    ushort_t* vt  = (ushort_t*)(ws + 41943040);         // v^T (h1 overlays)
    ushort_t* h1  = (ushort_t*)(ws + 41943040);
    ushort_t* ao  = (ushort_t*)(ws + 50331648);
    float*    wf  = (float*)(ws + 58720256);            // 16.78 MB
    ushort_t* wt  = (ushort_t*)(ws + 75497472);         // 14 slices of 512KB
    float*    stats = (float*)(ws + 75497472 + 14 * 524288);   // 5*8192*2 f32
    float*    uArr  = stats + STATS_F;                  // 4608
    float*    vArr  = uArr + UV_F;                      // 4608
    const size_t WSL = (size_t)D_ * D_;

    zero_kernel<<<89, 256, 0, stream>>>(stats);
    convert_w_kernel<<<13 * 64, 256, 0, stream>>>(Wq, Wk, Wv, Wo, W1, W2, fc0_w,
                                                  ln1_s, ln2_s, lnf_s, wt);
    uv_kernel<<<dim3(9, 4), 256, 0, stream>>>(Wq, Wk, Wv, W1, fc0_w,
                                              ln1_s, ln1_b, ln2_s, ln2_b, lnf_s, lnf_b,
                                              uArr, vArr);
    prep_kernel<<<dim3(4, 8, 32), 256, 0, stream>>>(x, epos, pos_tab, enc, hi, stats);

    for (int l = 0; l < 2; l++) {
        size_t o1 = (size_t)l * D_;
        const ushort_t* WqkvT = wt + (l * 6 + 0) * WSL;
        const ushort_t* WoT = wt + (l * 6 + 3) * WSL;
        const ushort_t* W1T = wt + (l * 6 + 4) * WSL;
        const ushort_t* W2T = wt + (l * 6 + 5) * WSL;
        float* stQKV = stats + (l == 0 ? 0 : 2) * 8192 * 2;   // prep / W2(l0)
        float* stWo  = stats + (l == 0 ? 1 : 3) * 8192 * 2;
        float* stW2  = stats + (l == 0 ? 2 : 4) * 8192 * 2;

        gemm_qkv_kernel<<<768, 256, 0, stream>>>(hi, WqkvT, bq + o1, bk + o1, bv + o1,
                                                 stQKV, uArr + l * 1536, vArr + l * 1536, qb);
        attn_fused_kernel<<<dim3(4, 256), 256, 0, stream>>>(qb, kb, vt, ao);
        // Wo: producer (enc += ao@Wo + bo), stats -> stWo
        gemm_kernel<2><<<512, 256, 0, stream>>>(ao, nullptr, WoT, nullptr, 1, 8,
                                                bo + o1, enc, enc, hi, nullptr,
                                                nullptr, nullptr, nullptr, stWo);
        // W1: fold consumer (ln2) + relu
        gemm_kernel<3><<<512, 256, 0, stream>>>(hi, nullptr, W1T, nullptr, 1, 8,
                                                b1 + o1, nullptr, nullptr, h1, nullptr,
                                                stWo, uArr + 3072 + l * 512, vArr + 3072 + l * 512, nullptr);
        // W2: producer (enc += h1@W2 + b2); l==1 also writes lo, skips f32 out
        if (l == 0)
            gemm_kernel<2><<<512, 256, 0, stream>>>(h1, nullptr, W2T, nullptr, 1, 8,
                                                    b2 + o1, enc, enc, hi, nullptr,
                                                    nullptr, nullptr, nullptr, stW2);
        else
            gemm_kernel<6><<<512, 256, 0, stream>>>(h1, nullptr, W2T, nullptr, 1, 8,
                                                    b2 + o1, enc, nullptr, hi, lo,
                                                    nullptr, nullptr, nullptr, stW2);
    }

    // fc0: fold consumer (lnf), 2-seg split-bf16 (Ah*Wh + Al*Wh)
    gemm_kernel<4><<<512, 256, 0, stream>>>(hi, lo, wt + 12 * WSL, wt + 12 * WSL, 2, 8,
                                            fc0_b, nullptr, wf, nullptr, nullptr,
                                            stats + 4 * 8192 * 2, uArr + 4096, vArr + 4096, nullptr);
    scores_kernel<<<dim3(8, 32, 5), 256, 0, stream>>>(wf, gpos, emb, fc1_w, scb);
    wsum_kernel<<<dim3(5, 32), 256, 0, stream>>>(scb, wf, (float*)d_out);
}

// Round 12
// 288.671 us; speedup vs baseline: 1.1273x; 1.1273x over previous
//
#include <hip/hip_runtime.h>
#include <math.h>

#define B_ 32
#define D_ 512
#define T_ 256
#define NH_ 8
#define DK_ 64
#define ML_ 25

typedef unsigned short ushort_t;
using short8 = __attribute__((ext_vector_type(8))) short;
using f32x4  = __attribute__((ext_vector_type(4))) float;

__device__ __forceinline__ ushort_t f2bf(float f) {
    unsigned u = __float_as_uint(f);
    unsigned r = (u + 0x7fffu + ((u >> 16) & 1u)) >> 16;
    return (ushort_t)r;
}
__device__ __forceinline__ float bf2f(ushort_t h) {
    return __uint_as_float(((unsigned)h) << 16);
}
__device__ __forceinline__ void gl16(const void* g, void* l) {
    __builtin_amdgcn_global_load_lds((const __attribute__((address_space(1))) void*)g,
                                     (__attribute__((address_space(3))) void*)l, 16, 0, 0);
}
#define ZERO4(v) { (v)[0]=0.f; (v)[1]=0.f; (v)[2]=0.f; (v)[3]=0.f; }

// ---------------- prep: enc[b,t,c] = x[b,c,t]*sqrt(512) + pos[epos[t],c]  (LDS transpose) ----------------
__global__ __launch_bounds__(256) void prep_kernel(const float* __restrict__ x,
                                                   const int* __restrict__ epos,
                                                   const float* __restrict__ pos,
                                                   float* __restrict__ enc) {
    __shared__ float ld[64][65];
    int tt = blockIdx.x, ct = blockIdx.y, b = blockIdx.z;
    int t0 = tt * 64, c0 = ct * 64;
    int tid = threadIdx.x;
    int r = tid >> 4, c4 = (tid & 15) << 2;
#pragma unroll
    for (int p = 0; p < 4; p++) {
        int row = p * 16 + r;  // channel within tile
        float4 v = *(const float4*)(x + ((size_t)(b * D_ + c0 + row) * T_ + t0) + c4);
        ld[row][c4 + 0] = v.x; ld[row][c4 + 1] = v.y; ld[row][c4 + 2] = v.z; ld[row][c4 + 3] = v.w;
    }
    __syncthreads();
#pragma unroll
    for (int p = 0; p < 4; p++) {
        int tr = p * 16 + r;   // token within tile
        int ep = epos[t0 + tr];
        float4 pv = *(const float4*)(pos + (size_t)ep * D_ + c0 + c4);
        float4 o;
        o.x = ld[c4 + 0][tr] * 22.627417f + pv.x;
        o.y = ld[c4 + 1][tr] * 22.627417f + pv.y;
        o.z = ld[c4 + 2][tr] * 22.627417f + pv.z;
        o.w = ld[c4 + 3][tr] * 22.627417f + pv.w;
        *(float4*)(enc + (size_t)(b * T_ + t0 + tr) * D_ + c0 + c4) = o;
    }
}

// ---------------- weight convert: WT[n][k] = bf16(W[k][n]); fc0 also lo ----------------
__global__ __launch_bounds__(256) void convert_w_kernel(const float* __restrict__ Wq,
                                                        const float* __restrict__ Wk,
                                                        const float* __restrict__ Wv,
                                                        const float* __restrict__ Wo,
                                                        const float* __restrict__ W1,
                                                        const float* __restrict__ W2,
                                                        const float* __restrict__ fc0,
                                                        ushort_t* __restrict__ wt) {
    __shared__ float ld[64][65];
    int m = blockIdx.x >> 6;
    int tile = blockIdx.x & 63;
    int tn = tile >> 3, tk = tile & 7;
    int n0 = tn * 64, k0 = tk * 64;
    const float* src;
    if (m < 12) {
        int l = m / 6, w = m % 6;
        const float* bases[6] = {Wq, Wk, Wv, Wo, W1, W2};
        src = bases[w] + (size_t)l * D_ * D_;
    } else {
        src = fc0;
    }
    int tid = threadIdx.x;
    int r = tid >> 4, c4 = (tid & 15) << 2;
#pragma unroll
    for (int p = 0; p < 4; p++) {
        int row = p * 16 + r;  // k index
        float4 v = *(const float4*)(src + (size_t)(k0 + row) * D_ + n0 + c4);
        ld[row][c4 + 0] = v.x; ld[row][c4 + 1] = v.y; ld[row][c4 + 2] = v.z; ld[row][c4 + 3] = v.w;
    }
    __syncthreads();
    ushort_t* dsth = wt + (size_t)m * D_ * D_;
    ushort_t* dstl = wt + (size_t)13 * D_ * D_;
#pragma unroll
    for (int p = 0; p < 4; p++) {
        int n = p * 16 + r;
        int kc = c4;
        ushort_t h[4], lo[4];
#pragma unroll
        for (int i = 0; i < 4; i++) {
            float f = ld[kc + i][n];
            h[i] = f2bf(f);
            lo[i] = f2bf(f - bf2f(h[i]));
        }
        *(ushort4*)(dsth + (size_t)(n0 + n) * D_ + k0 + kc) = make_ushort4(h[0], h[1], h[2], h[3]);
        if (m == 12)
            *(ushort4*)(dstl + (size_t)(n0 + n) * D_ + k0 + kc) = make_ushort4(lo[0], lo[1], lo[2], lo[3]);
    }
}

// ---------------- LayerNorm -> bf16 hi (+lo) ----------------
template<bool LO>
__global__ __launch_bounds__(256) void ln_kernel(const float* __restrict__ x,
                                                 const float* __restrict__ s,
                                                 const float* __restrict__ b,
                                                 ushort_t* __restrict__ yh,
                                                 ushort_t* __restrict__ yl) {
    int wid = threadIdx.x >> 6, lane = threadIdx.x & 63;
    size_t row = (size_t)blockIdx.x * 4 + wid;
    const float4* xr = (const float4*)(x + row * D_);
    float4 v0 = xr[lane * 2], v1 = xr[lane * 2 + 1];
    float sum = v0.x + v0.y + v0.z + v0.w + v1.x + v1.y + v1.z + v1.w;
    for (int o = 32; o; o >>= 1) sum += __shfl_xor(sum, o);
    float mean = sum * (1.f / 512.f);
    float d[8] = {v0.x - mean, v0.y - mean, v0.z - mean, v0.w - mean,
                  v1.x - mean, v1.y - mean, v1.z - mean, v1.w - mean};
    float vs = 0.f;
#pragma unroll
    for (int i = 0; i < 8; i++) vs += d[i] * d[i];
    for (int o = 32; o; o >>= 1) vs += __shfl_xor(vs, o);
    float rs = 1.f / sqrtf(vs * (1.f / 512.f) + 1e-5f);
    const float4* s4 = (const float4*)s;
    const float4* b4 = (const float4*)b;
    float4 sa = s4[lane * 2], sb = s4[lane * 2 + 1];
    float4 ba = b4[lane * 2], bb = b4[lane * 2 + 1];
    float o8[8];
    o8[0] = d[0] * rs * sa.x + ba.x; o8[1] = d[1] * rs * sa.y + ba.y;
    o8[2] = d[2] * rs * sa.z + ba.z; o8[3] = d[3] * rs * sa.w + ba.w;
    o8[4] = d[4] * rs * sb.x + bb.x; o8[5] = d[5] * rs * sb.y + bb.y;
    o8[6] = d[6] * rs * sb.z + bb.z; o8[7] = d[7] * rs * sb.w + bb.w;
    ushort_t h[8];
#pragma unroll
    for (int i = 0; i < 8; i++) h[i] = f2bf(o8[i]);
    uint4 u;
    u.x = (unsigned)h[0] | ((unsigned)h[1] << 16);
    u.y = (unsigned)h[2] | ((unsigned)h[3] << 16);
    u.z = (unsigned)h[4] | ((unsigned)h[5] << 16);
    u.w = (unsigned)h[6] | ((unsigned)h[7] << 16);
    *(uint4*)(yh + row * D_ + lane * 8) = u;
    if (LO) {
        ushort_t l8[8];
#pragma unroll
        for (int i = 0; i < 8; i++) l8[i] = f2bf(o8[i] - bf2f(h[i]));
        uint4 ul;
        ul.x = (unsigned)l8[0] | ((unsigned)l8[1] << 16);
        ul.y = (unsigned)l8[2] | ((unsigned)l8[3] << 16);
        ul.z = (unsigned)l8[4] | ((unsigned)l8[5] << 16);
        ul.w = (unsigned)l8[6] | ((unsigned)l8[7] << 16);
        *(uint4*)(yl + row * D_ + lane * 8) = ul;
    }
}

// ---------------- MFMA GEMM (N=512 ops): tile 128x64, 3-buffer counted-vmcnt (round-8 proven) ----------------
// EPI: 2=f32(+bias+res), 3=relu->bf16, 4=f32(+bias)
template<int EPI>
__global__ __launch_bounds__(256) void gemm_kernel(const ushort_t* __restrict__ A0,
                                                   const ushort_t* __restrict__ A1,
                                                   const ushort_t* __restrict__ B0,
                                                   const ushort_t* __restrict__ B1,
                                                   int nseg, int nbn,
                                                   const float* __restrict__ bias,
                                                   const float* __restrict__ res,
                                                   float* __restrict__ outF,
                                                   ushort_t* __restrict__ outB) {
    __shared__ ushort_t As[3][128 * 64];
    __shared__ ushort_t Bs[3][64 * 64];
    int tid = threadIdx.x;
    int g = blockIdx.x;
    int per = gridDim.x >> 3;
    int lin = (g & 7) * per + (g >> 3);
    int bm = lin / nbn, bn = lin % nbn;

    int lane = tid & 63;
    int wid = tid >> 6;
    int wm = wid >> 1, wn = wid & 1;       // wave owns 64x32 of the 128x64 tile
    int xr = (lane & 7) << 3;

    f32x4 acc[4][2];
#pragma unroll
    for (int i = 0; i < 4; i++)
#pragma unroll
        for (int j = 0; j < 2; j++) ZERO4(acc[i][j]);

    int nt = nseg * 8;

#define STAGE(kt, buf)                                                                  \
    {                                                                                   \
        int seg_ = (kt) >> 3;                                                           \
        int k0_ = ((kt) & 7) * 64;                                                      \
        const ushort_t* Asg = seg_ == 0 ? A0 : A1;                                      \
        const ushort_t* Bsg = seg_ == 0 ? B0 : B1;                                      \
        _Pragma("unroll")                                                               \
        for (int it = 0; it < 4; it++) {                                                \
            int uu = tid + it * 256;                                                    \
            int row_ = uu >> 3;                                                         \
            int kb_ = (((uu & 7) ^ (row_ & 7)) << 3);                                   \
            gl16(Asg + (size_t)(bm * 128 + row_) * 512 + k0_ + kb_, &As[buf][uu * 8]);  \
        }                                                                               \
        _Pragma("unroll")                                                               \
        for (int it = 0; it < 2; it++) {                                                \
            int uu = tid + it * 256;                                                    \
            int row_ = uu >> 3;                                                         \
            int kb_ = (((uu & 7) ^ (row_ & 7)) << 3);                                   \
            gl16(Bsg + (size_t)(bn * 64 + row_) * 512 + k0_ + kb_, &Bs[buf][uu * 8]);   \
        }                                                                               \
    }

#define COMPUTE(bufc)                                                                        \
    {                                                                                        \
        _Pragma("unroll")                                                                    \
        for (int kc = 0; kc < 2; kc++) {                                                     \
            short8 a[4], b[2];                                                               \
            int koff = (kc * 32 + ((lane >> 4) << 3)) ^ xr;                                  \
            _Pragma("unroll")                                                                \
            for (int i = 0; i < 4; i++)                                                      \
                a[i] = *(const short8*)&As[bufc][(wm * 64 + i * 16 + (lane & 15)) * 64 + koff]; \
            _Pragma("unroll")                                                                \
            for (int j = 0; j < 2; j++)                                                      \
                b[j] = *(const short8*)&Bs[bufc][(wn * 32 + j * 16 + (lane & 15)) * 64 + koff]; \
            _Pragma("unroll")                                                                \
            for (int i = 0; i < 4; i++)                                                      \
                _Pragma("unroll")                                                            \
                for (int j = 0; j < 2; j++)                                                  \
                    acc[i][j] = __builtin_amdgcn_mfma_f32_16x16x32_bf16(a[i], b[j], acc[i][j], 0, 0, 0); \
        }                                                                                    \
    }

    STAGE(0, 0);
    if (nt > 1) STAGE(1, 1);
    asm volatile("s_waitcnt vmcnt(6)" ::: "memory");
    __builtin_amdgcn_s_barrier();

    int cur = 0;
    for (int t = 0; t < nt; t++) {
        if (t + 2 < nt) STAGE(t + 2, (cur + 2 >= 3 ? cur - 1 : cur + 2));   // (cur+2)%3
        COMPUTE(cur);
        if (t + 2 < nt) {
            asm volatile("s_waitcnt vmcnt(6)" ::: "memory");
        } else if (t + 1 < nt) {
            asm volatile("s_waitcnt vmcnt(0)" ::: "memory");
        }
        __builtin_amdgcn_s_barrier();
        cur = (cur == 2) ? 0 : cur + 1;
    }
#undef STAGE
#undef COMPUTE

#pragma unroll
    for (int i = 0; i < 4; i++) {
#pragma unroll
        for (int j = 0; j < 2; j++) {
            int r0 = bm * 128 + wm * 64 + i * 16 + ((lane >> 4) << 2);
            int col = bn * 64 + wn * 32 + j * 16 + (lane & 15);
            float bc = bias[col];
#pragma unroll
            for (int jj = 0; jj < 4; jj++) {
                float v = acc[i][j][jj] + bc;
                int row = r0 + jj;
                size_t idx = (size_t)row * 512 + col;
                if (EPI == 2) {
                    outF[idx] = v + res[idx];
                } else if (EPI == 3) {
                    outB[idx] = f2bf(fmaxf(v, 0.f));
                } else {
                    outF[idx] = v;
                }
            }
        }
    }
}

// ---------------- wide MFMA GEMM for fused QKV: tile 128x128, N=1536, 2-buffer stage-early ----------------
__global__ __launch_bounds__(256) void gemm_qkv_kernel(const ushort_t* __restrict__ A,
                                                       const ushort_t* __restrict__ W,
                                                       const float* __restrict__ bq,
                                                       const float* __restrict__ bk,
                                                       const float* __restrict__ bv,
                                                       ushort_t* __restrict__ outB) {
    __shared__ ushort_t As[2][128 * 64];
    __shared__ ushort_t Bs[2][128 * 64];
    int tid = threadIdx.x;
    int g = blockIdx.x;
    int per = gridDim.x >> 3;                 // grid 768 -> 96
    int lin = (g & 7) * per + (g >> 3);
    int bm = lin / 12, bn = lin % 12;

    int lane = tid & 63;
    int wid = tid >> 6;
    int wm = wid >> 1, wn = wid & 1;          // wave owns 64x64 of the 128x128 tile
    int xr = (lane & 7) << 3;

    f32x4 acc[4][4];
#pragma unroll
    for (int i = 0; i < 4; i++)
#pragma unroll
        for (int j = 0; j < 4; j++) ZERO4(acc[i][j]);

#define QSTAGE(kt, buf)                                                                 \
    {                                                                                   \
        int k0_ = (kt) * 64;                                                            \
        _Pragma("unroll")                                                               \
        for (int it = 0; it < 4; it++) {                                                \
            int uu = tid + it * 256;                                                    \
            int row_ = uu >> 3;                                                         \
            int kb_ = (((uu & 7) ^ (row_ & 7)) << 3);                                   \
            gl16(A + (size_t)(bm * 128 + row_) * 512 + k0_ + kb_, &As[buf][uu * 8]);    \
            gl16(W + (size_t)(bn * 128 + row_) * 512 + k0_ + kb_, &Bs[buf][uu * 8]);    \
        }                                                                               \
    }

    QSTAGE(0, 0);
    asm volatile("s_waitcnt vmcnt(0)" ::: "memory");
    __builtin_amdgcn_s_barrier();

    int buf = 0;
    for (int t = 0; t < 8; t++) {
        if (t + 1 < 8) QSTAGE(t + 1, buf ^ 1);
#pragma unroll
        for (int kc = 0; kc < 2; kc++) {
            short8 a[4], b[4];
            int koff = (kc * 32 + ((lane >> 4) << 3)) ^ xr;
#pragma unroll
            for (int i = 0; i < 4; i++)
                a[i] = *(const short8*)&As[buf][(wm * 64 + i * 16 + (lane & 15)) * 64 + koff];
#pragma unroll
            for (int j = 0; j < 4; j++)
                b[j] = *(const short8*)&Bs[buf][(wn * 64 + j * 16 + (lane & 15)) * 64 + koff];
#pragma unroll
            for (int i = 0; i < 4; i++)
#pragma unroll
                for (int j = 0; j < 4; j++)
                    acc[i][j] = __builtin_amdgcn_mfma_f32_16x16x32_bf16(a[i], b[j], acc[i][j], 0, 0, 0);
        }
        if (t + 1 < 8) asm volatile("s_waitcnt vmcnt(0)" ::: "memory");
        __builtin_amdgcn_s_barrier();
        buf ^= 1;
    }
#undef QSTAGE

#pragma unroll
    for (int i = 0; i < 4; i++) {
#pragma unroll
        for (int j = 0; j < 4; j++) {
            int r0 = bm * 128 + wm * 64 + i * 16 + ((lane >> 4) << 2);
            int col = bn * 128 + wn * 64 + j * 16 + (lane & 15);
            int seg = col >> 9;
            int ccol = col & 511;
            const float* bp = (seg == 0) ? bq : (seg == 1 ? bk : bv);
            float bc = bp[ccol];
#pragma unroll
            for (int jj = 0; jj < 4; jj++) {
                float v = acc[i][j][jj] + bc;
                int row = r0 + jj;
                if (seg < 2) {
                    outB[(size_t)seg * 4194304 + (size_t)row * 512 + ccol] = f2bf(v);
                } else {
                    int bb2 = row >> 8, t2 = row & 255;
                    outB[(size_t)2 * 4194304 +
                         ((size_t)(bb2 * 8 + (ccol >> 6)) * 64 + (ccol & 63)) * 256 + t2] = f2bf(v);
                }
            }
        }
    }
}

// ---------------- fused attention: block = (64 q-rows, bh). QK^T -> softmax -> PV ----------------
__global__ __launch_bounds__(256) void attn_fused_kernel(const ushort_t* __restrict__ q,
                                                         const ushort_t* __restrict__ k,
                                                         const ushort_t* __restrict__ vt,
                                                         ushort_t* __restrict__ ao) {
    __shared__ ushort_t KVs[256 * 64];
    __shared__ ushort_t Ps[64 * 256];
    int tid = threadIdx.x;
    int lane = tid & 63;
    int wid = tid >> 6;
    int m0 = blockIdx.x * 64;
    int bh = blockIdx.y;
    int b = bh >> 3, h = bh & 7;
    int xr = (lane & 7) << 3;

#pragma unroll
    for (int it = 0; it < 8; it++) {
        int uu = tid + it * 256;
        int row = uu >> 3;
        int gx = ((uu & 7) ^ (row & 7)) << 3;
        gl16(k + (size_t)(b * T_ + row) * D_ + h * DK_ + gx, &KVs[uu * 8]);
    }
    short8 qa0, qa1;
    {
        int qrow = m0 + wid * 16 + (lane & 15);
        const ushort_t* qp = q + (size_t)(b * T_ + qrow) * D_ + h * DK_ + ((lane >> 4) << 3);
        qa0 = *(const short8*)(qp);
        qa1 = *(const short8*)(qp + 32);
    }
    f32x4 acc[16];
#pragma unroll
    for (int j = 0; j < 16; j++) ZERO4(acc[j]);
    asm volatile("s_waitcnt vmcnt(0)" ::: "memory");
    __syncthreads();

#pragma unroll
    for (int j = 0; j < 16; j++) {
        int krow = j * 16 + (lane & 15);
        short8 b0 = *(const short8*)&KVs[krow * 64 + ((((lane >> 4) << 3)) ^ xr)];
        short8 b1 = *(const short8*)&KVs[krow * 64 + ((32 + ((lane >> 4) << 3)) ^ xr)];
        acc[j] = __builtin_amdgcn_mfma_f32_16x16x32_bf16(qa0, b0, acc[j], 0, 0, 0);
        acc[j] = __builtin_amdgcn_mfma_f32_16x16x32_bf16(qa1, b1, acc[j], 0, 0, 0);
    }
    __syncthreads();

#pragma unroll
    for (int it = 0; it < 8; it++) {
        int uu = tid + it * 256;
        int row = uu >> 5;
        int gx = ((uu & 31) ^ (row & 7)) << 3;
        gl16(vt + ((size_t)bh * DK_ + row) * T_ + gx, &KVs[uu * 8]);
    }

    const float C = 0.125f * 1.44269504f;
#pragma unroll
    for (int jj = 0; jj < 4; jj++) {
        float mx = -1e30f;
#pragma unroll
        for (int j = 0; j < 16; j++) mx = fmaxf(mx, acc[j][jj]);
#pragma unroll
        for (int msk = 1; msk < 16; msk <<= 1) mx = fmaxf(mx, __shfl_xor(mx, msk));
        float sm = 0.f;
#pragma unroll
        for (int j = 0; j < 16; j++) {
            float e = __builtin_amdgcn_exp2f((acc[j][jj] - mx) * C);
            acc[j][jj] = e;
            sm += e;
        }
#pragma unroll
        for (int msk = 1; msk < 16; msk <<= 1) sm += __shfl_xor(sm, msk);
        float inv = 1.f / sm;
#pragma unroll
        for (int j = 0; j < 16; j++) acc[j][jj] *= inv;
    }
#pragma unroll
    for (int j = 0; j < 16; j++) {
#pragma unroll
        for (int jj = 0; jj < 4; jj++) {
            int row = wid * 16 + ((lane >> 4) << 2) + jj;
            int col = j * 16 + (lane & 15);
            Ps[row * 256 + (col ^ ((row & 7) << 3))] = f2bf(acc[j][jj]);
        }
    }
    asm volatile("s_waitcnt vmcnt(0)" ::: "memory");
    __syncthreads();

    int wm = wid >> 1, wn = wid & 1;
    f32x4 acc2[2][2];
#pragma unroll
    for (int i = 0; i < 2; i++)
#pragma unroll
        for (int j = 0; j < 2; j++) ZERO4(acc2[i][j]);
#pragma unroll
    for (int kc = 0; kc < 8; kc++) {
        int off = (kc * 32 + ((lane >> 4) << 3)) ^ xr;
        short8 a0 = *(const short8*)&Ps[(wm * 32 + (lane & 15)) * 256 + off];
        short8 a1 = *(const short8*)&Ps[(wm * 32 + 16 + (lane & 15)) * 256 + off];
        short8 b0 = *(const short8*)&KVs[(wn * 32 + (lane & 15)) * 256 + off];
        short8 b1 = *(const short8*)&KVs[(wn * 32 + 16 + (lane & 15)) * 256 + off];
        acc2[0][0] = __builtin_amdgcn_mfma_f32_16x16x32_bf16(a0, b0, acc2[0][0], 0, 0, 0);
        acc2[0][1] = __builtin_amdgcn_mfma_f32_16x16x32_bf16(a0, b1, acc2[0][1], 0, 0, 0);
        acc2[1][0] = __builtin_amdgcn_mfma_f32_16x16x32_bf16(a1, b0, acc2[1][0], 0, 0, 0);
        acc2[1][1] = __builtin_amdgcn_mfma_f32_16x16x32_bf16(a1, b1, acc2[1][1], 0, 0, 0);
    }
#pragma unroll
    for (int i = 0; i < 2; i++)
#pragma unroll
        for (int j = 0; j < 2; j++)
#pragma unroll
            for (int jj = 0; jj < 4; jj++)
                ao[(size_t)(b * T_ + m0 + wm * 32 + i * 16 + ((lane >> 4) << 2) + jj) * D_ +
                   h * DK_ + wn * 32 + j * 16 + (lane & 15)] = f2bf(acc2[i][j][jj]);
}

// ---------------- PVAM scores ----------------
__global__ __launch_bounds__(256) void scores_kernel(const float* __restrict__ wf,
                                                     const int* __restrict__ gpos,
                                                     const float* __restrict__ emb,
                                                     const float* __restrict__ w1,
                                                     float* __restrict__ scores) {
    __shared__ float wpL[5][512];
    __shared__ float w1m2[512];
    const float K2 = 2.885390082f;  // 2*log2(e)
    int tid = threadIdx.x;
    int b = blockIdx.y;
    int mg = blockIdx.z * 5;
    int t = blockIdx.x * 32 + (tid >> 3);
    int cg = tid & 7;
    for (int idx = tid; idx < 5 * 128; idx += 256) {
        int m = idx >> 7, w4 = idx & 127;
        float4 v = *(const float4*)(emb + (size_t)gpos[mg + m] * D_ + (w4 << 2));
        v.x *= K2; v.y *= K2; v.z *= K2; v.w *= K2;
        *(float4*)&wpL[m][w4 << 2] = v;
    }
    if (tid < 128) {
        float4 v = *(const float4*)(w1 + (tid << 2));
        v.x *= -2.f; v.y *= -2.f; v.z *= -2.f; v.w *= -2.f;
        *(float4*)&w1m2[tid << 2] = v;
    }
    float4 wfs[16];
    float W1S = 0.f;
    const float* wfr = wf + (size_t)(b * T_ + t) * D_ + (cg << 2);
#pragma unroll
    for (int j = 0; j < 16; j++) {
        float4 v = *(const float4*)(wfr + (j << 5));
        wfs[j].x = v.x * K2; wfs[j].y = v.y * K2; wfs[j].z = v.z * K2; wfs[j].w = v.w * K2;
        float4 wv = *(const float4*)(w1 + (cg << 2) + (j << 5));
        W1S += wv.x + wv.y + wv.z + wv.w;
    }
    __syncthreads();
    float s[5] = {W1S, W1S, W1S, W1S, W1S};
#pragma unroll
    for (int j = 0; j < 16; j++) {
        float4 w14 = *(const float4*)&w1m2[(cg << 2) + (j << 5)];
#pragma unroll
        for (int m = 0; m < 5; m++) {
            float4 wp4 = *(const float4*)&wpL[m][(cg << 2) + (j << 5)];
            s[m] += w14.x * __builtin_amdgcn_rcpf(__builtin_amdgcn_exp2f(wfs[j].x + wp4.x) + 1.f);
            s[m] += w14.y * __builtin_amdgcn_rcpf(__builtin_amdgcn_exp2f(wfs[j].y + wp4.y) + 1.f);
            s[m] += w14.z * __builtin_amdgcn_rcpf(__builtin_amdgcn_exp2f(wfs[j].z + wp4.z) + 1.f);
            s[m] += w14.w * __builtin_amdgcn_rcpf(__builtin_amdgcn_exp2f(wfs[j].w + wp4.w) + 1.f);
        }
    }
#pragma unroll
    for (int m = 0; m < 5; m++) {
        s[m] += __shfl_xor(s[m], 1);
        s[m] += __shfl_xor(s[m], 2);
        s[m] += __shfl_xor(s[m], 4);
    }
    if (cg == 0) {
#pragma unroll
        for (int m = 0; m < 5; m++)
            scores[((size_t)b * ML_ + mg + m) * T_ + t] = s[m];
    }
}

// weighted sum with fused softmax
__global__ __launch_bounds__(256) void wsum_kernel(const float* __restrict__ scores,
                                                   const float* __restrict__ wf,
                                                   float* __restrict__ out) {
    __shared__ float at[T_][8];
    __shared__ float redmax[4][8];
    __shared__ float redsum[4][8];
    int tid = threadIdx.x;
    int lane = tid & 63, wv = tid >> 6;
    int b = blockIdx.y, m0 = blockIdx.x * 5;
    float s[5];
#pragma unroll
    for (int q = 0; q < 5; q++)
        s[q] = scores[((size_t)b * ML_ + m0 + q) * T_ + tid];
#pragma unroll
    for (int q = 0; q < 5; q++) {
        float mx = s[q];
        for (int o = 32; o; o >>= 1) mx = fmaxf(mx, __shfl_xor(mx, o));
        if (lane == 0) redmax[wv][q] = mx;
    }
    __syncthreads();
    float e[5];
#pragma unroll
    for (int q = 0; q < 5; q++) {
        float m = fmaxf(fmaxf(redmax[0][q], redmax[1][q]), fmaxf(redmax[2][q], redmax[3][q]));
        e[q] = __expf(s[q] - m);
        float sm = e[q];
        for (int o = 32; o; o >>= 1) sm += __shfl_xor(sm, o);
        if (lane == 0) redsum[wv][q] = sm;
    }
    __syncthreads();
#pragma unroll
    for (int q = 0; q < 5; q++) {
        float sm = redsum[0][q] + redsum[1][q] + redsum[2][q] + redsum[3][q];
        at[tid][q] = e[q] / sm;
    }
    __syncthreads();
    int c0 = tid << 1;
    const float* wfb = wf + (size_t)b * T_ * D_ + c0;
    float acc[5][2] = {};
    for (int t = 0; t < T_; t++) {
        float2 v = *(const float2*)(wfb + (size_t)t * D_);
        float4 a4 = *(const float4*)&at[t][0];
        float a5 = at[t][4];
        acc[0][0] += a4.x * v.x; acc[0][1] += a4.x * v.y;
        acc[1][0] += a4.y * v.x; acc[1][1] += a4.y * v.y;
        acc[2][0] += a4.z * v.x; acc[2][1] += a4.z * v.y;
        acc[3][0] += a4.w * v.x; acc[3][1] += a4.w * v.y;
        acc[4][0] += a5 * v.x;   acc[4][1] += a5 * v.y;
    }
#pragma unroll
    for (int q = 0; q < 5; q++) {
        float2 o;
        o.x = acc[q][0]; o.y = acc[q][1];
        *(float2*)(out + ((size_t)b * ML_ + m0 + q) * D_ + c0) = o;
    }
}

extern "C" void kernel_launch(void* const* d_in, const int* in_sizes, int n_in,
                              void* d_out, int out_size, void* d_ws, size_t ws_size,
                              hipStream_t stream) {
    (void)in_sizes; (void)n_in; (void)out_size; (void)ws_size;
    const float* x        = (const float*)d_in[0];
    const int*   epos     = (const int*)d_in[1];
    const int*   gpos     = (const int*)d_in[2];
    const float* pos_tab  = (const float*)d_in[3];
    const float* ln1_s    = (const float*)d_in[4];
    const float* ln1_b    = (const float*)d_in[5];
    const float* Wq       = (const float*)d_in[6];
    const float* bq       = (const float*)d_in[7];
    const float* Wk       = (const float*)d_in[8];
    const float* bk       = (const float*)d_in[9];
    const float* Wv       = (const float*)d_in[10];
    const float* bv       = (const float*)d_in[11];
    const float* Wo       = (const float*)d_in[12];
    const float* bo       = (const float*)d_in[13];
    const float* ln2_s    = (const float*)d_in[14];
    const float* ln2_b    = (const float*)d_in[15];
    const float* W1       = (const float*)d_in[16];
    const float* b1       = (const float*)d_in[17];
    const float* W2       = (const float*)d_in[18];
    const float* b2       = (const float*)d_in[19];
    const float* lnf_s    = (const float*)d_in[20];
    const float* lnf_b    = (const float*)d_in[21];
    const float* fc0_w    = (const float*)d_in[22];
    const float* fc0_b    = (const float*)d_in[23];
    const float* emb      = (const float*)d_in[24];
    const float* fc1_w    = (const float*)d_in[25];

    char* ws = (char*)d_ws;
    float*    enc = (float*)(ws);                       // 16.78 MB
    ushort_t* hi  = (ushort_t*)(ws + 16777216);         // 8.39 MB
    ushort_t* qb  = (ushort_t*)(ws + 25165824);         // q
    ushort_t* kb  = (ushort_t*)(ws + 33554432);         // k (lo / scb overlay later)
    ushort_t* lo  = (ushort_t*)(ws + 33554432);
    float*    scb = (float*)(ws + 33554432);
    ushort_t* vt  = (ushort_t*)(ws + 41943040);         // v^T (h1 overlays)
    ushort_t* h1  = (ushort_t*)(ws + 41943040);
    ushort_t* ao  = (ushort_t*)(ws + 50331648);
    float*    wf  = (float*)(ws + 58720256);            // 16.78 MB
    ushort_t* wt  = (ushort_t*)(ws + 75497472);         // 14 slices of 512KB
    const size_t WSL = (size_t)D_ * D_;

    convert_w_kernel<<<13 * 64, 256, 0, stream>>>(Wq, Wk, Wv, Wo, W1, W2, fc0_w, wt);
    prep_kernel<<<dim3(4, 8, 32), 256, 0, stream>>>(x, epos, pos_tab, enc);

    for (int l = 0; l < 2; l++) {
        size_t o1 = (size_t)l * D_;
        const ushort_t* WqkvT = wt + (l * 6 + 0) * WSL;
        const ushort_t* WoT = wt + (l * 6 + 3) * WSL;
        const ushort_t* W1T = wt + (l * 6 + 4) * WSL;
        const ushort_t* W2T = wt + (l * 6 + 5) * WSL;

        ln_kernel<false><<<2048, 256, 0, stream>>>(enc, ln1_s + o1, ln1_b + o1, hi, nullptr);
        gemm_qkv_kernel<<<768, 256, 0, stream>>>(hi, WqkvT, bq + o1, bk + o1, bv + o1, qb);
        attn_fused_kernel<<<dim3(4, 256), 256, 0, stream>>>(qb, kb, vt, ao);
        gemm_kernel<2><<<512, 256, 0, stream>>>(ao, nullptr, WoT, nullptr, 1, 8,
                                                bo + o1, enc, enc, nullptr);
        ln_kernel<false><<<2048, 256, 0, stream>>>(enc, ln2_s + o1, ln2_b + o1, hi, nullptr);
        gemm_kernel<3><<<512, 256, 0, stream>>>(hi, nullptr, W1T, nullptr, 1, 8,
                                                b1 + o1, nullptr, nullptr, h1);
        gemm_kernel<2><<<512, 256, 0, stream>>>(h1, nullptr, W2T, nullptr, 1, 8,
                                                b2 + o1, enc, enc, nullptr);
    }

    ln_kernel<true><<<2048, 256, 0, stream>>>(enc, lnf_s, lnf_b, hi, lo);
    // fc0 split-bf16, 2-seg: Ah*Wh + Al*Wh (Ah*Wl dropped — proven absmax-neutral in r11)
    gemm_kernel<4><<<512, 256, 0, stream>>>(hi, lo, wt + 12 * WSL, wt + 12 * WSL, 2, 8,
                                            fc0_b, nullptr, wf, nullptr);
    scores_kernel<<<dim3(8, 32, 5), 256, 0, stream>>>(wf, gpos, emb, fc1_w, scb);
    wsum_kernel<<<dim3(5, 32), 256, 0, stream>>>(scb, wf, (float*)d_out);
}

// Round 13
// 276.630 us; speedup vs baseline: 1.1764x; 1.0435x over previous
//
#include <hip/hip_runtime.h>
#include <math.h>

#define B_ 32
#define D_ 512
#define T_ 256
#define NH_ 8
#define DK_ 64
#define ML_ 25

typedef unsigned short ushort_t;
using short8 = __attribute__((ext_vector_type(8))) short;
using f32x4  = __attribute__((ext_vector_type(4))) float;

__device__ __forceinline__ ushort_t f2bf(float f) {
    unsigned u = __float_as_uint(f);
    unsigned r = (u + 0x7fffu + ((u >> 16) & 1u)) >> 16;
    return (ushort_t)r;
}
__device__ __forceinline__ float bf2f(ushort_t h) {
    return __uint_as_float(((unsigned)h) << 16);
}
__device__ __forceinline__ void gl16(const void* g, void* l) {
    __builtin_amdgcn_global_load_lds((const __attribute__((address_space(1))) void*)g,
                                     (__attribute__((address_space(3))) void*)l, 16, 0, 0);
}
#define ZERO4(v) { (v)[0]=0.f; (v)[1]=0.f; (v)[2]=0.f; (v)[3]=0.f; }

// ---------------- prep: enc[b,t,c] = x[b,c,t]*sqrt(512) + pos[epos[t],c]  (LDS transpose) ----------------
__global__ __launch_bounds__(256) void prep_kernel(const float* __restrict__ x,
                                                   const int* __restrict__ epos,
                                                   const float* __restrict__ pos,
                                                   float* __restrict__ enc) {
    __shared__ float ld[64][65];
    int tt = blockIdx.x, ct = blockIdx.y, b = blockIdx.z;
    int t0 = tt * 64, c0 = ct * 64;
    int tid = threadIdx.x;
    int r = tid >> 4, c4 = (tid & 15) << 2;
#pragma unroll
    for (int p = 0; p < 4; p++) {
        int row = p * 16 + r;  // channel within tile
        float4 v = *(const float4*)(x + ((size_t)(b * D_ + c0 + row) * T_ + t0) + c4);
        ld[row][c4 + 0] = v.x; ld[row][c4 + 1] = v.y; ld[row][c4 + 2] = v.z; ld[row][c4 + 3] = v.w;
    }
    __syncthreads();
#pragma unroll
    for (int p = 0; p < 4; p++) {
        int tr = p * 16 + r;   // token within tile
        int ep = epos[t0 + tr];
        float4 pv = *(const float4*)(pos + (size_t)ep * D_ + c0 + c4);
        float4 o;
        o.x = ld[c4 + 0][tr] * 22.627417f + pv.x;
        o.y = ld[c4 + 1][tr] * 22.627417f + pv.y;
        o.z = ld[c4 + 2][tr] * 22.627417f + pv.z;
        o.w = ld[c4 + 3][tr] * 22.627417f + pv.w;
        *(float4*)(enc + (size_t)(b * T_ + t0 + tr) * D_ + c0 + c4) = o;
    }
}

// ---------------- weight convert: WT[n][k] = bf16(W[k][n]) ----------------
__global__ __launch_bounds__(256) void convert_w_kernel(const float* __restrict__ Wq,
                                                        const float* __restrict__ Wk,
                                                        const float* __restrict__ Wv,
                                                        const float* __restrict__ Wo,
                                                        const float* __restrict__ W1,
                                                        const float* __restrict__ W2,
                                                        const float* __restrict__ fc0,
                                                        ushort_t* __restrict__ wt) {
    __shared__ float ld[64][65];
    int m = blockIdx.x >> 6;
    int tile = blockIdx.x & 63;
    int tn = tile >> 3, tk = tile & 7;
    int n0 = tn * 64, k0 = tk * 64;
    const float* src;
    if (m < 12) {
        int l = m / 6, w = m % 6;
        const float* bases[6] = {Wq, Wk, Wv, Wo, W1, W2};
        src = bases[w] + (size_t)l * D_ * D_;
    } else {
        src = fc0;
    }
    int tid = threadIdx.x;
    int r = tid >> 4, c4 = (tid & 15) << 2;
#pragma unroll
    for (int p = 0; p < 4; p++) {
        int row = p * 16 + r;  // k index
        float4 v = *(const float4*)(src + (size_t)(k0 + row) * D_ + n0 + c4);
        ld[row][c4 + 0] = v.x; ld[row][c4 + 1] = v.y; ld[row][c4 + 2] = v.z; ld[row][c4 + 3] = v.w;
    }
    __syncthreads();
    ushort_t* dsth = wt + (size_t)m * D_ * D_;
#pragma unroll
    for (int p = 0; p < 4; p++) {
        int n = p * 16 + r;
        int kc = c4;
        ushort_t h[4];
#pragma unroll
        for (int i = 0; i < 4; i++) h[i] = f2bf(ld[kc + i][n]);
        *(ushort4*)(dsth + (size_t)(n0 + n) * D_ + k0 + kc) = make_ushort4(h[0], h[1], h[2], h[3]);
    }
}

// ---------------- LayerNorm -> bf16 ----------------
__global__ __launch_bounds__(256) void ln_kernel(const float* __restrict__ x,
                                                 const float* __restrict__ s,
                                                 const float* __restrict__ b,
                                                 ushort_t* __restrict__ yh) {
    int wid = threadIdx.x >> 6, lane = threadIdx.x & 63;
    size_t row = (size_t)blockIdx.x * 4 + wid;
    const float4* xr = (const float4*)(x + row * D_);
    float4 v0 = xr[lane * 2], v1 = xr[lane * 2 + 1];
    float sum = v0.x + v0.y + v0.z + v0.w + v1.x + v1.y + v1.z + v1.w;
    for (int o = 32; o; o >>= 1) sum += __shfl_xor(sum, o);
    float mean = sum * (1.f / 512.f);
    float d[8] = {v0.x - mean, v0.y - mean, v0.z - mean, v0.w - mean,
                  v1.x - mean, v1.y - mean, v1.z - mean, v1.w - mean};
    float vs = 0.f;
#pragma unroll
    for (int i = 0; i < 8; i++) vs += d[i] * d[i];
    for (int o = 32; o; o >>= 1) vs += __shfl_xor(vs, o);
    float rs = 1.f / sqrtf(vs * (1.f / 512.f) + 1e-5f);
    const float4* s4 = (const float4*)s;
    const float4* b4 = (const float4*)b;
    float4 sa = s4[lane * 2], sb = s4[lane * 2 + 1];
    float4 ba = b4[lane * 2], bb = b4[lane * 2 + 1];
    float o8[8];
    o8[0] = d[0] * rs * sa.x + ba.x; o8[1] = d[1] * rs * sa.y + ba.y;
    o8[2] = d[2] * rs * sa.z + ba.z; o8[3] = d[3] * rs * sa.w + ba.w;
    o8[4] = d[4] * rs * sb.x + bb.x; o8[5] = d[5] * rs * sb.y + bb.y;
    o8[6] = d[6] * rs * sb.z + bb.z; o8[7] = d[7] * rs * sb.w + bb.w;
    ushort_t h[8];
#pragma unroll
    for (int i = 0; i < 8; i++) h[i] = f2bf(o8[i]);
    uint4 u;
    u.x = (unsigned)h[0] | ((unsigned)h[1] << 16);
    u.y = (unsigned)h[2] | ((unsigned)h[3] << 16);
    u.z = (unsigned)h[4] | ((unsigned)h[5] << 16);
    u.w = (unsigned)h[6] | ((unsigned)h[7] << 16);
    *(uint4*)(yh + row * D_ + lane * 8) = u;
}

// ---------------- MFMA GEMM (N=512 ops): tile 128x64, 3-buffer counted-vmcnt (round-8 proven) ----------------
// EPI: 2=f32(+bias+res), 3=relu->bf16, 4=f32(+bias)
template<int EPI>
__global__ __launch_bounds__(256) void gemm_kernel(const ushort_t* __restrict__ A0,
                                                   const ushort_t* __restrict__ B0,
                                                   int nbn,
                                                   const float* __restrict__ bias,
                                                   const float* __restrict__ res,
                                                   float* __restrict__ outF,
                                                   ushort_t* __restrict__ outB) {
    __shared__ ushort_t As[3][128 * 64];
    __shared__ ushort_t Bs[3][64 * 64];
    int tid = threadIdx.x;
    int g = blockIdx.x;
    int per = gridDim.x >> 3;
    int lin = (g & 7) * per + (g >> 3);
    int bm = lin / nbn, bn = lin % nbn;

    int lane = tid & 63;
    int wid = tid >> 6;
    int wm = wid >> 1, wn = wid & 1;       // wave owns 64x32 of the 128x64 tile
    int xr = (lane & 7) << 3;

    f32x4 acc[4][2];
#pragma unroll
    for (int i = 0; i < 4; i++)
#pragma unroll
        for (int j = 0; j < 2; j++) ZERO4(acc[i][j]);

    const int nt = 8;

#define STAGE(kt, buf)                                                                  \
    {                                                                                   \
        int k0_ = (kt) * 64;                                                            \
        _Pragma("unroll")                                                               \
        for (int it = 0; it < 4; it++) {                                                \
            int uu = tid + it * 256;                                                    \
            int row_ = uu >> 3;                                                         \
            int kb_ = (((uu & 7) ^ (row_ & 7)) << 3);                                   \
            gl16(A0 + (size_t)(bm * 128 + row_) * 512 + k0_ + kb_, &As[buf][uu * 8]);   \
        }                                                                               \
        _Pragma("unroll")                                                               \
        for (int it = 0; it < 2; it++) {                                                \
            int uu = tid + it * 256;                                                    \
            int row_ = uu >> 3;                                                         \
            int kb_ = (((uu & 7) ^ (row_ & 7)) << 3);                                   \
            gl16(B0 + (size_t)(bn * 64 + row_) * 512 + k0_ + kb_, &Bs[buf][uu * 8]);    \
        }                                                                               \
    }

#define COMPUTE(bufc)                                                                        \
    {                                                                                        \
        _Pragma("unroll")                                                                    \
        for (int kc = 0; kc < 2; kc++) {                                                     \
            short8 a[4], b[2];                                                               \
            int koff = (kc * 32 + ((lane >> 4) << 3)) ^ xr;                                  \
            _Pragma("unroll")                                                                \
            for (int i = 0; i < 4; i++)                                                      \
                a[i] = *(const short8*)&As[bufc][(wm * 64 + i * 16 + (lane & 15)) * 64 + koff]; \
            _Pragma("unroll")                                                                \
            for (int j = 0; j < 2; j++)                                                      \
                b[j] = *(const short8*)&Bs[bufc][(wn * 32 + j * 16 + (lane & 15)) * 64 + koff]; \
            _Pragma("unroll")                                                                \
            for (int i = 0; i < 4; i++)                                                      \
                _Pragma("unroll")                                                            \
                for (int j = 0; j < 2; j++)                                                  \
                    acc[i][j] = __builtin_amdgcn_mfma_f32_16x16x32_bf16(a[i], b[j], acc[i][j], 0, 0, 0); \
        }                                                                                    \
    }

    STAGE(0, 0);
    STAGE(1, 1);
    asm volatile("s_waitcnt vmcnt(6)" ::: "memory");
    __builtin_amdgcn_s_barrier();

    int cur = 0;
    for (int t = 0; t < nt; t++) {
        if (t + 2 < nt) STAGE(t + 2, (cur + 2 >= 3 ? cur - 1 : cur + 2));   // (cur+2)%3
        COMPUTE(cur);
        if (t + 2 < nt) {
            asm volatile("s_waitcnt vmcnt(6)" ::: "memory");
        } else if (t + 1 < nt) {
            asm volatile("s_waitcnt vmcnt(0)" ::: "memory");
        }
        __builtin_amdgcn_s_barrier();
        cur = (cur == 2) ? 0 : cur + 1;
    }
#undef STAGE
#undef COMPUTE

#pragma unroll
    for (int i = 0; i < 4; i++) {
#pragma unroll
        for (int j = 0; j < 2; j++) {
            int r0 = bm * 128 + wm * 64 + i * 16 + ((lane >> 4) << 2);
            int col = bn * 64 + wn * 32 + j * 16 + (lane & 15);
            float bc = bias[col];
#pragma unroll
            for (int jj = 0; jj < 4; jj++) {
                float v = acc[i][j][jj] + bc;
                int row = r0 + jj;
                size_t idx = (size_t)row * 512 + col;
                if (EPI == 2) {
                    outF[idx] = v + res[idx];
                } else if (EPI == 3) {
                    outB[idx] = f2bf(fmaxf(v, 0.f));
                } else {
                    outF[idx] = v;
                }
            }
        }
    }
}

// ---------------- wide MFMA GEMM for fused QKV: tile 128x128, N=1536, 2-buffer stage-early ----------------
__global__ __launch_bounds__(256) void gemm_qkv_kernel(const ushort_t* __restrict__ A,
                                                       const ushort_t* __restrict__ W,
                                                       const float* __restrict__ bq,
                                                       const float* __restrict__ bk,
                                                       const float* __restrict__ bv,
                                                       ushort_t* __restrict__ outB) {
    __shared__ ushort_t As[2][128 * 64];
    __shared__ ushort_t Bs[2][128 * 64];
    int tid = threadIdx.x;
    int g = blockIdx.x;
    int per = gridDim.x >> 3;                 // grid 768 -> 96
    int lin = (g & 7) * per + (g >> 3);
    int bm = lin / 12, bn = lin % 12;

    int lane = tid & 63;
    int wid = tid >> 6;
    int wm = wid >> 1, wn = wid & 1;          // wave owns 64x64 of the 128x128 tile
    int xr = (lane & 7) << 3;

    f32x4 acc[4][4];
#pragma unroll
    for (int i = 0; i < 4; i++)
#pragma unroll
        for (int j = 0; j < 4; j++) ZERO4(acc[i][j]);

#define QSTAGE(kt, buf)                                                                 \
    {                                                                                   \
        int k0_ = (kt) * 64;                                                            \
        _Pragma("unroll")                                                               \
        for (int it = 0; it < 4; it++) {                                                \
            int uu = tid + it * 256;                                                    \
            int row_ = uu >> 3;                                                         \
            int kb_ = (((uu & 7) ^ (row_ & 7)) << 3);                                   \
            gl16(A + (size_t)(bm * 128 + row_) * 512 + k0_ + kb_, &As[buf][uu * 8]);    \
            gl16(W + (size_t)(bn * 128 + row_) * 512 + k0_ + kb_, &Bs[buf][uu * 8]);    \
        }                                                                               \
    }

    QSTAGE(0, 0);
    asm volatile("s_waitcnt vmcnt(0)" ::: "memory");
    __builtin_amdgcn_s_barrier();

    int buf = 0;
    for (int t = 0; t < 8; t++) {
        if (t + 1 < 8) QSTAGE(t + 1, buf ^ 1);
#pragma unroll
        for (int kc = 0; kc < 2; kc++) {
            short8 a[4], b[4];
            int koff = (kc * 32 + ((lane >> 4) << 3)) ^ xr;
#pragma unroll
            for (int i = 0; i < 4; i++)
                a[i] = *(const short8*)&As[buf][(wm * 64 + i * 16 + (lane & 15)) * 64 + koff];
#pragma unroll
            for (int j = 0; j < 4; j++)
                b[j] = *(const short8*)&Bs[buf][(wn * 64 + j * 16 + (lane & 15)) * 64 + koff];
#pragma unroll
            for (int i = 0; i < 4; i++)
#pragma unroll
                for (int j = 0; j < 4; j++)
                    acc[i][j] = __builtin_amdgcn_mfma_f32_16x16x32_bf16(a[i], b[j], acc[i][j], 0, 0, 0);
        }
        if (t + 1 < 8) asm volatile("s_waitcnt vmcnt(0)" ::: "memory");
        __builtin_amdgcn_s_barrier();
        buf ^= 1;
    }
#undef QSTAGE

#pragma unroll
    for (int i = 0; i < 4; i++) {
#pragma unroll
        for (int j = 0; j < 4; j++) {
            int r0 = bm * 128 + wm * 64 + i * 16 + ((lane >> 4) << 2);
            int col = bn * 128 + wn * 64 + j * 16 + (lane & 15);
            int seg = col >> 9;
            int ccol = col & 511;
            const float* bp = (seg == 0) ? bq : (seg == 1 ? bk : bv);
            float bc = bp[ccol];
#pragma unroll
            for (int jj = 0; jj < 4; jj++) {
                float v = acc[i][j][jj] + bc;
                int row = r0 + jj;
                if (seg < 2) {
                    outB[(size_t)seg * 4194304 + (size_t)row * 512 + ccol] = f2bf(v);
                } else {
                    int bb2 = row >> 8, t2 = row & 255;
                    outB[(size_t)2 * 4194304 +
                         ((size_t)(bb2 * 8 + (ccol >> 6)) * 64 + (ccol & 63)) * 256 + t2] = f2bf(v);
                }
            }
        }
    }
}

// ---------------- fused attention: block = (64 q-rows, bh). QK^T -> softmax -> PV ----------------
__global__ __launch_bounds__(256) void attn_fused_kernel(const ushort_t* __restrict__ q,
                                                         const ushort_t* __restrict__ k,
                                                         const ushort_t* __restrict__ vt,
                                                         ushort_t* __restrict__ ao) {
    __shared__ ushort_t KVs[256 * 64];
    __shared__ ushort_t Ps[64 * 256];
    int tid = threadIdx.x;
    int lane = tid & 63;
    int wid = tid >> 6;
    int m0 = blockIdx.x * 64;
    int bh = blockIdx.y;
    int b = bh >> 3, h = bh & 7;
    int xr = (lane & 7) << 3;

#pragma unroll
    for (int it = 0; it < 8; it++) {
        int uu = tid + it * 256;
        int row = uu >> 3;
        int gx = ((uu & 7) ^ (row & 7)) << 3;
        gl16(k + (size_t)(b * T_ + row) * D_ + h * DK_ + gx, &KVs[uu * 8]);
    }
    short8 qa0, qa1;
    {
        int qrow = m0 + wid * 16 + (lane & 15);
        const ushort_t* qp = q + (size_t)(b * T_ + qrow) * D_ + h * DK_ + ((lane >> 4) << 3);
        qa0 = *(const short8*)(qp);
        qa1 = *(const short8*)(qp + 32);
    }
    f32x4 acc[16];
#pragma unroll
    for (int j = 0; j < 16; j++) ZERO4(acc[j]);
    asm volatile("s_waitcnt vmcnt(0)" ::: "memory");
    __syncthreads();

#pragma unroll
    for (int j = 0; j < 16; j++) {
        int krow = j * 16 + (lane & 15);
        short8 b0 = *(const short8*)&KVs[krow * 64 + ((((lane >> 4) << 3)) ^ xr)];
        short8 b1 = *(const short8*)&KVs[krow * 64 + ((32 + ((lane >> 4) << 3)) ^ xr)];
        acc[j] = __builtin_amdgcn_mfma_f32_16x16x32_bf16(qa0, b0, acc[j], 0, 0, 0);
        acc[j] = __builtin_amdgcn_mfma_f32_16x16x32_bf16(qa1, b1, acc[j], 0, 0, 0);
    }
    __syncthreads();

#pragma unroll
    for (int it = 0; it < 8; it++) {
        int uu = tid + it * 256;
        int row = uu >> 5;
        int gx = ((uu & 31) ^ (row & 7)) << 3;
        gl16(vt + ((size_t)bh * DK_ + row) * T_ + gx, &KVs[uu * 8]);
    }

    const float C = 0.125f * 1.44269504f;
#pragma unroll
    for (int jj = 0; jj < 4; jj++) {
        float mx = -1e30f;
#pragma unroll
        for (int j = 0; j < 16; j++) mx = fmaxf(mx, acc[j][jj]);
#pragma unroll
        for (int msk = 1; msk < 16; msk <<= 1) mx = fmaxf(mx, __shfl_xor(mx, msk));
        float sm = 0.f;
#pragma unroll
        for (int j = 0; j < 16; j++) {
            float e = __builtin_amdgcn_exp2f((acc[j][jj] - mx) * C);
            acc[j][jj] = e;
            sm += e;
        }
#pragma unroll
        for (int msk = 1; msk < 16; msk <<= 1) sm += __shfl_xor(sm, msk);
        float inv = 1.f / sm;
#pragma unroll
        for (int j = 0; j < 16; j++) acc[j][jj] *= inv;
    }
#pragma unroll
    for (int j = 0; j < 16; j++) {
#pragma unroll
        for (int jj = 0; jj < 4; jj++) {
            int row = wid * 16 + ((lane >> 4) << 2) + jj;
            int col = j * 16 + (lane & 15);
            Ps[row * 256 + (col ^ ((row & 7) << 3))] = f2bf(acc[j][jj]);
        }
    }
    asm volatile("s_waitcnt vmcnt(0)" ::: "memory");
    __syncthreads();

    int wm = wid >> 1, wn = wid & 1;
    f32x4 acc2[2][2];
#pragma unroll
    for (int i = 0; i < 2; i++)
#pragma unroll
        for (int j = 0; j < 2; j++) ZERO4(acc2[i][j]);
#pragma unroll
    for (int kc = 0; kc < 8; kc++) {
        int off = (kc * 32 + ((lane >> 4) << 3)) ^ xr;
        short8 a0 = *(const short8*)&Ps[(wm * 32 + (lane & 15)) * 256 + off];
        short8 a1 = *(const short8*)&Ps[(wm * 32 + 16 + (lane & 15)) * 256 + off];
        short8 b0 = *(const short8*)&KVs[(wn * 32 + (lane & 15)) * 256 + off];
        short8 b1 = *(const short8*)&KVs[(wn * 32 + 16 + (lane & 15)) * 256 + off];
        acc2[0][0] = __builtin_amdgcn_mfma_f32_16x16x32_bf16(a0, b0, acc2[0][0], 0, 0, 0);
        acc2[0][1] = __builtin_amdgcn_mfma_f32_16x16x32_bf16(a0, b1, acc2[0][1], 0, 0, 0);
        acc2[1][0] = __builtin_amdgcn_mfma_f32_16x16x32_bf16(a1, b0, acc2[1][0], 0, 0, 0);
        acc2[1][1] = __builtin_amdgcn_mfma_f32_16x16x32_bf16(a1, b1, acc2[1][1], 0, 0, 0);
    }
#pragma unroll
    for (int i = 0; i < 2; i++)
#pragma unroll
        for (int j = 0; j < 2; j++)
#pragma unroll
            for (int jj = 0; jj < 4; jj++)
                ao[(size_t)(b * T_ + m0 + wm * 32 + i * 16 + ((lane >> 4) << 2) + jj) * D_ +
                   h * DK_ + wn * 32 + j * 16 + (lane & 15)] = f2bf(acc2[i][j][jj]);
}

// ---------------- PVAM scores ----------------
__global__ __launch_bounds__(256) void scores_kernel(const float* __restrict__ wf,
                                                     const int* __restrict__ gpos,
                                                     const float* __restrict__ emb,
                                                     const float* __restrict__ w1,
                                                     float* __restrict__ scores) {
    __shared__ float wpL[5][512];
    __shared__ float w1m2[512];
    const float K2 = 2.885390082f;  // 2*log2(e)
    int tid = threadIdx.x;
    int b = blockIdx.y;
    int mg = blockIdx.z * 5;
    int t = blockIdx.x * 32 + (tid >> 3);
    int cg = tid & 7;
    for (int idx = tid; idx < 5 * 128; idx += 256) {
        int m = idx >> 7, w4 = idx & 127;
        float4 v = *(const float4*)(emb + (size_t)gpos[mg + m] * D_ + (w4 << 2));
        v.x *= K2; v.y *= K2; v.z *= K2; v.w *= K2;
        *(float4*)&wpL[m][w4 << 2] = v;
    }
    if (tid < 128) {
        float4 v = *(const float4*)(w1 + (tid << 2));
        v.x *= -2.f; v.y *= -2.f; v.z *= -2.f; v.w *= -2.f;
        *(float4*)&w1m2[tid << 2] = v;
    }
    float4 wfs[16];
    float W1S = 0.f;
    const float* wfr = wf + (size_t)(b * T_ + t) * D_ + (cg << 2);
#pragma unroll
    for (int j = 0; j < 16; j++) {
        float4 v = *(const float4*)(wfr + (j << 5));
        wfs[j].x = v.x * K2; wfs[j].y = v.y * K2; wfs[j].z = v.z * K2; wfs[j].w = v.w * K2;
        float4 wv = *(const float4*)(w1 + (cg << 2) + (j << 5));
        W1S += wv.x + wv.y + wv.z + wv.w;
    }
    __syncthreads();
    float s[5] = {W1S, W1S, W1S, W1S, W1S};
#pragma unroll
    for (int j = 0; j < 16; j++) {
        float4 w14 = *(const float4*)&w1m2[(cg << 2) + (j << 5)];
#pragma unroll
        for (int m = 0; m < 5; m++) {
            float4 wp4 = *(const float4*)&wpL[m][(cg << 2) + (j << 5)];
            s[m] += w14.x * __builtin_amdgcn_rcpf(__builtin_amdgcn_exp2f(wfs[j].x + wp4.x) + 1.f);
            s[m] += w14.y * __builtin_amdgcn_rcpf(__builtin_amdgcn_exp2f(wfs[j].y + wp4.y) + 1.f);
            s[m] += w14.z * __builtin_amdgcn_rcpf(__builtin_amdgcn_exp2f(wfs[j].z + wp4.z) + 1.f);
            s[m] += w14.w * __builtin_amdgcn_rcpf(__builtin_amdgcn_exp2f(wfs[j].w + wp4.w) + 1.f);
        }
    }
#pragma unroll
    for (int m = 0; m < 5; m++) {
        s[m] += __shfl_xor(s[m], 1);
        s[m] += __shfl_xor(s[m], 2);
        s[m] += __shfl_xor(s[m], 4);
    }
    if (cg == 0) {
#pragma unroll
        for (int m = 0; m < 5; m++)
            scores[((size_t)b * ML_ + mg + m) * T_ + t] = s[m];
    }
}

// weighted sum with fused softmax
__global__ __launch_bounds__(256) void wsum_kernel(const float* __restrict__ scores,
                                                   const float* __restrict__ wf,
                                                   float* __restrict__ out) {
    __shared__ float at[T_][8];
    __shared__ float redmax[4][8];
    __shared__ float redsum[4][8];
    int tid = threadIdx.x;
    int lane = tid & 63, wv = tid >> 6;
    int b = blockIdx.y, m0 = blockIdx.x * 5;
    float s[5];
#pragma unroll
    for (int q = 0; q < 5; q++)
        s[q] = scores[((size_t)b * ML_ + m0 + q) * T_ + tid];
#pragma unroll
    for (int q = 0; q < 5; q++) {
        float mx = s[q];
        for (int o = 32; o; o >>= 1) mx = fmaxf(mx, __shfl_xor(mx, o));
        if (lane == 0) redmax[wv][q] = mx;
    }
    __syncthreads();
    float e[5];
#pragma unroll
    for (int q = 0; q < 5; q++) {
        float m = fmaxf(fmaxf(redmax[0][q], redmax[1][q]), fmaxf(redmax[2][q], redmax[3][q]));
        e[q] = __expf(s[q] - m);
        float sm = e[q];
        for (int o = 32; o; o >>= 1) sm += __shfl_xor(sm, o);
        if (lane == 0) redsum[wv][q] = sm;
    }
    __syncthreads();
#pragma unroll
    for (int q = 0; q < 5; q++) {
        float sm = redsum[0][q] + redsum[1][q] + redsum[2][q] + redsum[3][q];
        at[tid][q] = e[q] / sm;
    }
    __syncthreads();
    int c0 = tid << 1;
    const float* wfb = wf + (size_t)b * T_ * D_ + c0;
    float acc[5][2] = {};
    for (int t = 0; t < T_; t++) {
        float2 v = *(const float2*)(wfb + (size_t)t * D_);
        float4 a4 = *(const float4*)&at[t][0];
        float a5 = at[t][4];
        acc[0][0] += a4.x * v.x; acc[0][1] += a4.x * v.y;
        acc[1][0] += a4.y * v.x; acc[1][1] += a4.y * v.y;
        acc[2][0] += a4.z * v.x; acc[2][1] += a4.z * v.y;
        acc[3][0] += a4.w * v.x; acc[3][1] += a4.w * v.y;
        acc[4][0] += a5 * v.x;   acc[4][1] += a5 * v.y;
    }
#pragma unroll
    for (int q = 0; q < 5; q++) {
        float2 o;
        o.x = acc[q][0]; o.y = acc[q][1];
        *(float2*)(out + ((size_t)b * ML_ + m0 + q) * D_ + c0) = o;
    }
}

extern "C" void kernel_launch(void* const* d_in, const int* in_sizes, int n_in,
                              void* d_out, int out_size, void* d_ws, size_t ws_size,
                              hipStream_t stream) {
    (void)in_sizes; (void)n_in; (void)out_size; (void)ws_size;
    const float* x        = (const float*)d_in[0];
    const int*   epos     = (const int*)d_in[1];
    const int*   gpos     = (const int*)d_in[2];
    const float* pos_tab  = (const float*)d_in[3];
    const float* ln1_s    = (const float*)d_in[4];
    const float* ln1_b    = (const float*)d_in[5];
    const float* Wq       = (const float*)d_in[6];
    const float* bq       = (const float*)d_in[7];
    const float* Wk       = (const float*)d_in[8];
    const float* bk       = (const float*)d_in[9];
    const float* Wv       = (const float*)d_in[10];
    const float* bv       = (const float*)d_in[11];
    const float* Wo       = (const float*)d_in[12];
    const float* bo       = (const float*)d_in[13];
    const float* ln2_s    = (const float*)d_in[14];
    const float* ln2_b    = (const float*)d_in[15];
    const float* W1       = (const float*)d_in[16];
    const float* b1       = (const float*)d_in[17];
    const float* W2       = (const float*)d_in[18];
    const float* b2       = (const float*)d_in[19];
    const float* lnf_s    = (const float*)d_in[20];
    const float* lnf_b    = (const float*)d_in[21];
    const float* fc0_w    = (const float*)d_in[22];
    const float* fc0_b    = (const float*)d_in[23];
    const float* emb      = (const float*)d_in[24];
    const float* fc1_w    = (const float*)d_in[25];

    char* ws = (char*)d_ws;
    float*    enc = (float*)(ws);                       // 16.78 MB
    ushort_t* hi  = (ushort_t*)(ws + 16777216);         // 8.39 MB
    ushort_t* qb  = (ushort_t*)(ws + 25165824);         // q
    ushort_t* kb  = (ushort_t*)(ws + 33554432);         // k (scb overlay later)
    float*    scb = (float*)(ws + 33554432);
    ushort_t* vt  = (ushort_t*)(ws + 41943040);         // v^T (h1 overlays)
    ushort_t* h1  = (ushort_t*)(ws + 41943040);
    ushort_t* ao  = (ushort_t*)(ws + 50331648);
    float*    wf  = (float*)(ws + 58720256);            // 16.78 MB
    ushort_t* wt  = (ushort_t*)(ws + 75497472);         // 13 slices of 512KB
    const size_t WSL = (size_t)D_ * D_;

    convert_w_kernel<<<13 * 64, 256, 0, stream>>>(Wq, Wk, Wv, Wo, W1, W2, fc0_w, wt);
    prep_kernel<<<dim3(4, 8, 32), 256, 0, stream>>>(x, epos, pos_tab, enc);

    for (int l = 0; l < 2; l++) {
        size_t o1 = (size_t)l * D_;
        const ushort_t* WqkvT = wt + (l * 6 + 0) * WSL;
        const ushort_t* WoT = wt + (l * 6 + 3) * WSL;
        const ushort_t* W1T = wt + (l * 6 + 4) * WSL;
        const ushort_t* W2T = wt + (l * 6 + 5) * WSL;

        ln_kernel<<<2048, 256, 0, stream>>>(enc, ln1_s + o1, ln1_b + o1, hi);
        gemm_qkv_kernel<<<768, 256, 0, stream>>>(hi, WqkvT, bq + o1, bk + o1, bv + o1, qb);
        attn_fused_kernel<<<dim3(4, 256), 256, 0, stream>>>(qb, kb, vt, ao);
        gemm_kernel<2><<<512, 256, 0, stream>>>(ao, WoT, 8, bo + o1, enc, enc, nullptr);
        ln_kernel<<<2048, 256, 0, stream>>>(enc, ln2_s + o1, ln2_b + o1, hi);
        gemm_kernel<3><<<512, 256, 0, stream>>>(hi, W1T, 8, b1 + o1, nullptr, nullptr, h1);
        gemm_kernel<2><<<512, 256, 0, stream>>>(h1, W2T, 8, b2 + o1, enc, enc, nullptr);
    }

    ln_kernel<<<2048, 256, 0, stream>>>(enc, lnf_s, lnf_b, hi);
    // fc0: plain bf16 1-seg (both low-order split products proven absmax-neutral in r11/r12)
    gemm_kernel<4><<<512, 256, 0, stream>>>(hi, wt + 12 * WSL, 8, fc0_b, nullptr, wf, nullptr);
    scores_kernel<<<dim3(8, 32, 5), 256, 0, stream>>>(wf, gpos, emb, fc1_w, scb);
    wsum_kernel<<<dim3(5, 32), 256, 0, stream>>>(scb, wf, (float*)d_out);
}

// Round 14
// 264.852 us; speedup vs baseline: 1.2287x; 1.0445x over previous
//
#include <hip/hip_runtime.h>
#include <math.h>

#define B_ 32
#define D_ 512
#define T_ 256
#define NH_ 8
#define DK_ 64
#define ML_ 25

typedef unsigned short ushort_t;
using short8 = __attribute__((ext_vector_type(8))) short;
using f32x4  = __attribute__((ext_vector_type(4))) float;

__device__ __forceinline__ ushort_t f2bf(float f) {
    unsigned u = __float_as_uint(f);
    unsigned r = (u + 0x7fffu + ((u >> 16) & 1u)) >> 16;
    return (ushort_t)r;
}
__device__ __forceinline__ float bf2f(unsigned h) {
    return __uint_as_float(h << 16);
}
__device__ __forceinline__ void gl16(const void* g, void* l) {
    __builtin_amdgcn_global_load_lds((const __attribute__((address_space(1))) void*)g,
                                     (__attribute__((address_space(3))) void*)l, 16, 0, 0);
}
#define ZERO4(v) { (v)[0]=0.f; (v)[1]=0.f; (v)[2]=0.f; (v)[3]=0.f; }

// ---------------- prep: enc[b,t,c] = bf16(x[b,c,t]*sqrt(512) + pos[epos[t],c])  (LDS transpose) ----------------
__global__ __launch_bounds__(256) void prep_kernel(const float* __restrict__ x,
                                                   const int* __restrict__ epos,
                                                   const float* __restrict__ pos,
                                                   ushort_t* __restrict__ enc) {
    __shared__ float ld[64][65];
    int tt = blockIdx.x, ct = blockIdx.y, b = blockIdx.z;
    int t0 = tt * 64, c0 = ct * 64;
    int tid = threadIdx.x;
    int r = tid >> 4, c4 = (tid & 15) << 2;
#pragma unroll
    for (int p = 0; p < 4; p++) {
        int row = p * 16 + r;  // channel within tile
        float4 v = *(const float4*)(x + ((size_t)(b * D_ + c0 + row) * T_ + t0) + c4);
        ld[row][c4 + 0] = v.x; ld[row][c4 + 1] = v.y; ld[row][c4 + 2] = v.z; ld[row][c4 + 3] = v.w;
    }
    __syncthreads();
#pragma unroll
    for (int p = 0; p < 4; p++) {
        int tr = p * 16 + r;   // token within tile
        int ep = epos[t0 + tr];
        float4 pv = *(const float4*)(pos + (size_t)ep * D_ + c0 + c4);
        float4 o;
        o.x = ld[c4 + 0][tr] * 22.627417f + pv.x;
        o.y = ld[c4 + 1][tr] * 22.627417f + pv.y;
        o.z = ld[c4 + 2][tr] * 22.627417f + pv.z;
        o.w = ld[c4 + 3][tr] * 22.627417f + pv.w;
        *(ushort4*)(enc + (size_t)(b * T_ + t0 + tr) * D_ + c0 + c4) =
            make_ushort4(f2bf(o.x), f2bf(o.y), f2bf(o.z), f2bf(o.w));
    }
}

// ---------------- weight convert: WT[n][k] = bf16(W[k][n]) ----------------
__global__ __launch_bounds__(256) void convert_w_kernel(const float* __restrict__ Wq,
                                                        const float* __restrict__ Wk,
                                                        const float* __restrict__ Wv,
                                                        const float* __restrict__ Wo,
                                                        const float* __restrict__ W1,
                                                        const float* __restrict__ W2,
                                                        const float* __restrict__ fc0,
                                                        ushort_t* __restrict__ wt) {
    __shared__ float ld[64][65];
    int m = blockIdx.x >> 6;
    int tile = blockIdx.x & 63;
    int tn = tile >> 3, tk = tile & 7;
    int n0 = tn * 64, k0 = tk * 64;
    const float* src;
    if (m < 12) {
        int l = m / 6, w = m % 6;
        const float* bases[6] = {Wq, Wk, Wv, Wo, W1, W2};
        src = bases[w] + (size_t)l * D_ * D_;
    } else {
        src = fc0;
    }
    int tid = threadIdx.x;
    int r = tid >> 4, c4 = (tid & 15) << 2;
#pragma unroll
    for (int p = 0; p < 4; p++) {
        int row = p * 16 + r;  // k index
        float4 v = *(const float4*)(src + (size_t)(k0 + row) * D_ + n0 + c4);
        ld[row][c4 + 0] = v.x; ld[row][c4 + 1] = v.y; ld[row][c4 + 2] = v.z; ld[row][c4 + 3] = v.w;
    }
    __syncthreads();
    ushort_t* dsth = wt + (size_t)m * D_ * D_;
#pragma unroll
    for (int p = 0; p < 4; p++) {
        int n = p * 16 + r;
        int kc = c4;
        ushort_t h[4];
#pragma unroll
        for (int i = 0; i < 4; i++) h[i] = f2bf(ld[kc + i][n]);
        *(ushort4*)(dsth + (size_t)(n0 + n) * D_ + k0 + kc) = make_ushort4(h[0], h[1], h[2], h[3]);
    }
}

// ---------------- LayerNorm (bf16 in) -> bf16 out ----------------
__global__ __launch_bounds__(256) void ln_kernel(const ushort_t* __restrict__ x,
                                                 const float* __restrict__ s,
                                                 const float* __restrict__ b,
                                                 ushort_t* __restrict__ yh) {
    int wid = threadIdx.x >> 6, lane = threadIdx.x & 63;
    size_t row = (size_t)blockIdx.x * 4 + wid;
    uint4 u = *(const uint4*)(x + row * D_ + lane * 8);
    float v[8];
    v[0] = bf2f(u.x & 0xffffu); v[1] = bf2f(u.x >> 16);
    v[2] = bf2f(u.y & 0xffffu); v[3] = bf2f(u.y >> 16);
    v[4] = bf2f(u.z & 0xffffu); v[5] = bf2f(u.z >> 16);
    v[6] = bf2f(u.w & 0xffffu); v[7] = bf2f(u.w >> 16);
    float sum = 0.f;
#pragma unroll
    for (int i = 0; i < 8; i++) sum += v[i];
    for (int o = 32; o; o >>= 1) sum += __shfl_xor(sum, o);
    float mean = sum * (1.f / 512.f);
    float d[8];
#pragma unroll
    for (int i = 0; i < 8; i++) d[i] = v[i] - mean;
    float vs = 0.f;
#pragma unroll
    for (int i = 0; i < 8; i++) vs += d[i] * d[i];
    for (int o = 32; o; o >>= 1) vs += __shfl_xor(vs, o);
    float rs = 1.f / sqrtf(vs * (1.f / 512.f) + 1e-5f);
    const float4* s4 = (const float4*)s;
    const float4* b4 = (const float4*)b;
    float4 sa = s4[lane * 2], sb = s4[lane * 2 + 1];
    float4 ba = b4[lane * 2], bb = b4[lane * 2 + 1];
    float o8[8];
    o8[0] = d[0] * rs * sa.x + ba.x; o8[1] = d[1] * rs * sa.y + ba.y;
    o8[2] = d[2] * rs * sa.z + ba.z; o8[3] = d[3] * rs * sa.w + ba.w;
    o8[4] = d[4] * rs * sb.x + bb.x; o8[5] = d[5] * rs * sb.y + bb.y;
    o8[6] = d[6] * rs * sb.z + bb.z; o8[7] = d[7] * rs * sb.w + bb.w;
    ushort_t h[8];
#pragma unroll
    for (int i = 0; i < 8; i++) h[i] = f2bf(o8[i]);
    uint4 uo;
    uo.x = (unsigned)h[0] | ((unsigned)h[1] << 16);
    uo.y = (unsigned)h[2] | ((unsigned)h[3] << 16);
    uo.z = (unsigned)h[4] | ((unsigned)h[5] << 16);
    uo.w = (unsigned)h[6] | ((unsigned)h[7] << 16);
    *(uint4*)(yh + row * D_ + lane * 8) = uo;
}

// ---------------- MFMA GEMM (N=512 ops): tile 128x64, 3-buffer counted-vmcnt (round-8 proven) ----------------
// EPI: 2=bf16(+bias+bf16 res, in place), 3=relu->bf16, 4=f32(+bias)
template<int EPI>
__global__ __launch_bounds__(256) void gemm_kernel(const ushort_t* __restrict__ A0,
                                                   const ushort_t* __restrict__ B0,
                                                   int nbn,
                                                   const float* __restrict__ bias,
                                                   const ushort_t* __restrict__ resB,
                                                   float* __restrict__ outF,
                                                   ushort_t* __restrict__ outB) {
    __shared__ ushort_t As[3][128 * 64];
    __shared__ ushort_t Bs[3][64 * 64];
    int tid = threadIdx.x;
    int g = blockIdx.x;
    int per = gridDim.x >> 3;
    int lin = (g & 7) * per + (g >> 3);
    int bm = lin / nbn, bn = lin % nbn;

    int lane = tid & 63;
    int wid = tid >> 6;
    int wm = wid >> 1, wn = wid & 1;       // wave owns 64x32 of the 128x64 tile
    int xr = (lane & 7) << 3;

    f32x4 acc[4][2];
#pragma unroll
    for (int i = 0; i < 4; i++)
#pragma unroll
        for (int j = 0; j < 2; j++) ZERO4(acc[i][j]);

    const int nt = 8;

#define STAGE(kt, buf)                                                                  \
    {                                                                                   \
        int k0_ = (kt) * 64;                                                            \
        _Pragma("unroll")                                                               \
        for (int it = 0; it < 4; it++) {                                                \
            int uu = tid + it * 256;                                                    \
            int row_ = uu >> 3;                                                         \
            int kb_ = (((uu & 7) ^ (row_ & 7)) << 3);                                   \
            gl16(A0 + (size_t)(bm * 128 + row_) * 512 + k0_ + kb_, &As[buf][uu * 8]);   \
        }                                                                               \
        _Pragma("unroll")                                                               \
        for (int it = 0; it < 2; it++) {                                                \
            int uu = tid + it * 256;                                                    \
            int row_ = uu >> 3;                                                         \
            int kb_ = (((uu & 7) ^ (row_ & 7)) << 3);                                   \
            gl16(B0 + (size_t)(bn * 64 + row_) * 512 + k0_ + kb_, &Bs[buf][uu * 8]);    \
        }                                                                               \
    }

#define COMPUTE(bufc)                                                                        \
    {                                                                                        \
        _Pragma("unroll")                                                                    \
        for (int kc = 0; kc < 2; kc++) {                                                     \
            short8 a[4], b[2];                                                               \
            int koff = (kc * 32 + ((lane >> 4) << 3)) ^ xr;                                  \
            _Pragma("unroll")                                                                \
            for (int i = 0; i < 4; i++)                                                      \
                a[i] = *(const short8*)&As[bufc][(wm * 64 + i * 16 + (lane & 15)) * 64 + koff]; \
            _Pragma("unroll")                                                                \
            for (int j = 0; j < 2; j++)                                                      \
                b[j] = *(const short8*)&Bs[bufc][(wn * 32 + j * 16 + (lane & 15)) * 64 + koff]; \
            _Pragma("unroll")                                                                \
            for (int i = 0; i < 4; i++)                                                      \
                _Pragma("unroll")                                                            \
                for (int j = 0; j < 2; j++)                                                  \
                    acc[i][j] = __builtin_amdgcn_mfma_f32_16x16x32_bf16(a[i], b[j], acc[i][j], 0, 0, 0); \
        }                                                                                    \
    }

    STAGE(0, 0);
    STAGE(1, 1);
    asm volatile("s_waitcnt vmcnt(6)" ::: "memory");
    __builtin_amdgcn_s_barrier();

    int cur = 0;
    for (int t = 0; t < nt; t++) {
        if (t + 2 < nt) STAGE(t + 2, (cur + 2 >= 3 ? cur - 1 : cur + 2));   // (cur+2)%3
        COMPUTE(cur);
        if (t + 2 < nt) {
            asm volatile("s_waitcnt vmcnt(6)" ::: "memory");
        } else if (t + 1 < nt) {
            asm volatile("s_waitcnt vmcnt(0)" ::: "memory");
        }
        __builtin_amdgcn_s_barrier();
        cur = (cur == 2) ? 0 : cur + 1;
    }
#undef STAGE
#undef COMPUTE

#pragma unroll
    for (int i = 0; i < 4; i++) {
#pragma unroll
        for (int j = 0; j < 2; j++) {
            int r0 = bm * 128 + wm * 64 + i * 16 + ((lane >> 4) << 2);
            int col = bn * 64 + wn * 32 + j * 16 + (lane & 15);
            float bc = bias[col];
#pragma unroll
            for (int jj = 0; jj < 4; jj++) {
                float v = acc[i][j][jj] + bc;
                int row = r0 + jj;
                size_t idx = (size_t)row * 512 + col;
                if (EPI == 2) {
                    outB[idx] = f2bf(v + bf2f(resB[idx]));
                } else if (EPI == 3) {
                    outB[idx] = f2bf(fmaxf(v, 0.f));
                } else {
                    outF[idx] = v;
                }
            }
        }
    }
}

// ---------------- wide MFMA GEMM for fused QKV: tile 128x128, N=1536, 2-buffer stage-early ----------------
__global__ __launch_bounds__(256) void gemm_qkv_kernel(const ushort_t* __restrict__ A,
                                                       const ushort_t* __restrict__ W,
                                                       const float* __restrict__ bq,
                                                       const float* __restrict__ bk,
                                                       const float* __restrict__ bv,
                                                       ushort_t* __restrict__ outB) {
    __shared__ ushort_t As[2][128 * 64];
    __shared__ ushort_t Bs[2][128 * 64];
    int tid = threadIdx.x;
    int g = blockIdx.x;
    int per = gridDim.x >> 3;                 // grid 768 -> 96
    int lin = (g & 7) * per + (g >> 3);
    int bm = lin / 12, bn = lin % 12;

    int lane = tid & 63;
    int wid = tid >> 6;
    int wm = wid >> 1, wn = wid & 1;          // wave owns 64x64 of the 128x128 tile
    int xr = (lane & 7) << 3;

    f32x4 acc[4][4];
#pragma unroll
    for (int i = 0; i < 4; i++)
#pragma unroll
        for (int j = 0; j < 4; j++) ZERO4(acc[i][j]);

#define QSTAGE(kt, buf)                                                                 \
    {                                                                                   \
        int k0_ = (kt) * 64;                                                            \
        _Pragma("unroll")                                                               \
        for (int it = 0; it < 4; it++) {                                                \
            int uu = tid + it * 256;                                                    \
            int row_ = uu >> 3;                                                         \
            int kb_ = (((uu & 7) ^ (row_ & 7)) << 3);                                   \
            gl16(A + (size_t)(bm * 128 + row_) * 512 + k0_ + kb_, &As[buf][uu * 8]);    \
            gl16(W + (size_t)(bn * 128 + row_) * 512 + k0_ + kb_, &Bs[buf][uu * 8]);    \
        }                                                                               \
    }

    QSTAGE(0, 0);
    asm volatile("s_waitcnt vmcnt(0)" ::: "memory");
    __builtin_amdgcn_s_barrier();

    int buf = 0;
    for (int t = 0; t < 8; t++) {
        if (t + 1 < 8) QSTAGE(t + 1, buf ^ 1);
#pragma unroll
        for (int kc = 0; kc < 2; kc++) {
            short8 a[4], b[4];
            int koff = (kc * 32 + ((lane >> 4) << 3)) ^ xr;
#pragma unroll
            for (int i = 0; i < 4; i++)
                a[i] = *(const short8*)&As[buf][(wm * 64 + i * 16 + (lane & 15)) * 64 + koff];
#pragma unroll
            for (int j = 0; j < 4; j++)
                b[j] = *(const short8*)&Bs[buf][(wn * 64 + j * 16 + (lane & 15)) * 64 + koff];
#pragma unroll
            for (int i = 0; i < 4; i++)
#pragma unroll
                for (int j = 0; j < 4; j++)
                    acc[i][j] = __builtin_amdgcn_mfma_f32_16x16x32_bf16(a[i], b[j], acc[i][j], 0, 0, 0);
        }
        if (t + 1 < 8) asm volatile("s_waitcnt vmcnt(0)" ::: "memory");
        __builtin_amdgcn_s_barrier();
        buf ^= 1;
    }
#undef QSTAGE

#pragma unroll
    for (int i = 0; i < 4; i++) {
#pragma unroll
        for (int j = 0; j < 4; j++) {
            int r0 = bm * 128 + wm * 64 + i * 16 + ((lane >> 4) << 2);
            int col = bn * 128 + wn * 64 + j * 16 + (lane & 15);
            int seg = col >> 9;
            int ccol = col & 511;
            const float* bp = (seg == 0) ? bq : (seg == 1 ? bk : bv);
            float bc = bp[ccol];
#pragma unroll
            for (int jj = 0; jj < 4; jj++) {
                float v = acc[i][j][jj] + bc;
                int row = r0 + jj;
                if (seg < 2) {
                    outB[(size_t)seg * 4194304 + (size_t)row * 512 + ccol] = f2bf(v);
                } else {
                    int bb2 = row >> 8, t2 = row & 255;
                    outB[(size_t)2 * 4194304 +
                         ((size_t)(bb2 * 8 + (ccol >> 6)) * 64 + (ccol & 63)) * 256 + t2] = f2bf(v);
                }
            }
        }
    }
}

// ---------------- fused attention: block = (64 q-rows, bh). QK^T -> softmax -> PV ----------------
__global__ __launch_bounds__(256) void attn_fused_kernel(const ushort_t* __restrict__ q,
                                                         const ushort_t* __restrict__ k,
                                                         const ushort_t* __restrict__ vt,
                                                         ushort_t* __restrict__ ao) {
    __shared__ ushort_t KVs[256 * 64];
    __shared__ ushort_t Ps[64 * 256];
    int tid = threadIdx.x;
    int lane = tid & 63;
    int wid = tid >> 6;
    int m0 = blockIdx.x * 64;
    int bh = blockIdx.y;
    int b = bh >> 3, h = bh & 7;
    int xr = (lane & 7) << 3;

#pragma unroll
    for (int it = 0; it < 8; it++) {
        int uu = tid + it * 256;
        int row = uu >> 3;
        int gx = ((uu & 7) ^ (row & 7)) << 3;
        gl16(k + (size_t)(b * T_ + row) * D_ + h * DK_ + gx, &KVs[uu * 8]);
    }
    short8 qa0, qa1;
    {
        int qrow = m0 + wid * 16 + (lane & 15);
        const ushort_t* qp = q + (size_t)(b * T_ + qrow) * D_ + h * DK_ + ((lane >> 4) << 3);
        qa0 = *(const short8*)(qp);
        qa1 = *(const short8*)(qp + 32);
    }
    f32x4 acc[16];
#pragma unroll
    for (int j = 0; j < 16; j++) ZERO4(acc[j]);
    asm volatile("s_waitcnt vmcnt(0)" ::: "memory");
    __syncthreads();

#pragma unroll
    for (int j = 0; j < 16; j++) {
        int krow = j * 16 + (lane & 15);
        short8 b0 = *(const short8*)&KVs[krow * 64 + ((((lane >> 4) << 3)) ^ xr)];
        short8 b1 = *(const short8*)&KVs[krow * 64 + ((32 + ((lane >> 4) << 3)) ^ xr)];
        acc[j] = __builtin_amdgcn_mfma_f32_16x16x32_bf16(qa0, b0, acc[j], 0, 0, 0);
        acc[j] = __builtin_amdgcn_mfma_f32_16x16x32_bf16(qa1, b1, acc[j], 0, 0, 0);
    }
    __syncthreads();

#pragma unroll
    for (int it = 0; it < 8; it++) {
        int uu = tid + it * 256;
        int row = uu >> 5;
        int gx = ((uu & 31) ^ (row & 7)) << 3;
        gl16(vt + ((size_t)bh * DK_ + row) * T_ + gx, &KVs[uu * 8]);
    }

    const float C = 0.125f * 1.44269504f;
#pragma unroll
    for (int jj = 0; jj < 4; jj++) {
        float mx = -1e30f;
#pragma unroll
        for (int j = 0; j < 16; j++) mx = fmaxf(mx, acc[j][jj]);
#pragma unroll
        for (int msk = 1; msk < 16; msk <<= 1) mx = fmaxf(mx, __shfl_xor(mx, msk));
        float sm = 0.f;
#pragma unroll
        for (int j = 0; j < 16; j++) {
            float e = __builtin_amdgcn_exp2f((acc[j][jj] - mx) * C);
            acc[j][jj] = e;
            sm += e;
        }
#pragma unroll
        for (int msk = 1; msk < 16; msk <<= 1) sm += __shfl_xor(sm, msk);
        float inv = 1.f / sm;
#pragma unroll
        for (int j = 0; j < 16; j++) acc[j][jj] *= inv;
    }
#pragma unroll
    for (int j = 0; j < 16; j++) {
#pragma unroll
        for (int jj = 0; jj < 4; jj++) {
            int row = wid * 16 + ((lane >> 4) << 2) + jj;
            int col = j * 16 + (lane & 15);
            Ps[row * 256 + (col ^ ((row & 7) << 3))] = f2bf(acc[j][jj]);
        }
    }
    asm volatile("s_waitcnt vmcnt(0)" ::: "memory");
    __syncthreads();

    int wm = wid >> 1, wn = wid & 1;
    f32x4 acc2[2][2];
#pragma unroll
    for (int i = 0; i < 2; i++)
#pragma unroll
        for (int j = 0; j < 2; j++) ZERO4(acc2[i][j]);
#pragma unroll
    for (int kc = 0; kc < 8; kc++) {
        int off = (kc * 32 + ((lane >> 4) << 3)) ^ xr;
        short8 a0 = *(const short8*)&Ps[(wm * 32 + (lane & 15)) * 256 + off];
        short8 a1 = *(const short8*)&Ps[(wm * 32 + 16 + (lane & 15)) * 256 + off];
        short8 b0 = *(const short8*)&KVs[(wn * 32 + (lane & 15)) * 256 + off];
        short8 b1 = *(const short8*)&KVs[(wn * 32 + 16 + (lane & 15)) * 256 + off];
        acc2[0][0] = __builtin_amdgcn_mfma_f32_16x16x32_bf16(a0, b0, acc2[0][0], 0, 0, 0);
        acc2[0][1] = __builtin_amdgcn_mfma_f32_16x16x32_bf16(a0, b1, acc2[0][1], 0, 0, 0);
        acc2[1][0] = __builtin_amdgcn_mfma_f32_16x16x32_bf16(a1, b0, acc2[1][0], 0, 0, 0);
        acc2[1][1] = __builtin_amdgcn_mfma_f32_16x16x32_bf16(a1, b1, acc2[1][1], 0, 0, 0);
    }
#pragma unroll
    for (int i = 0; i < 2; i++)
#pragma unroll
        for (int j = 0; j < 2; j++)
#pragma unroll
            for (int jj = 0; jj < 4; jj++)
                ao[(size_t)(b * T_ + m0 + wm * 32 + i * 16 + ((lane >> 4) << 2) + jj) * D_ +
                   h * DK_ + wn * 32 + j * 16 + (lane & 15)] = f2bf(acc2[i][j][jj]);
}

// ---------------- PVAM scores ----------------
__global__ __launch_bounds__(256) void scores_kernel(const float* __restrict__ wf,
                                                     const int* __restrict__ gpos,
                                                     const float* __restrict__ emb,
                                                     const float* __restrict__ w1,
                                                     float* __restrict__ scores) {
    __shared__ float wpL[5][512];
    __shared__ float w1m2[512];
    const float K2 = 2.885390082f;  // 2*log2(e)
    int tid = threadIdx.x;
    int b = blockIdx.y;
    int mg = blockIdx.z * 5;
    int t = blockIdx.x * 32 + (tid >> 3);
    int cg = tid & 7;
    for (int idx = tid; idx < 5 * 128; idx += 256) {
        int m = idx >> 7, w4 = idx & 127;
        float4 v = *(const float4*)(emb + (size_t)gpos[mg + m] * D_ + (w4 << 2));
        v.x *= K2; v.y *= K2; v.z *= K2; v.w *= K2;
        *(float4*)&wpL[m][w4 << 2] = v;
    }
    if (tid < 128) {
        float4 v = *(const float4*)(w1 + (tid << 2));
        v.x *= -2.f; v.y *= -2.f; v.z *= -2.f; v.w *= -2.f;
        *(float4*)&w1m2[tid << 2] = v;
    }
    float4 wfs[16];
    float W1S = 0.f;
    const float* wfr = wf + (size_t)(b * T_ + t) * D_ + (cg << 2);
#pragma unroll
    for (int j = 0; j < 16; j++) {
        float4 v = *(const float4*)(wfr + (j << 5));
        wfs[j].x = v.x * K2; wfs[j].y = v.y * K2; wfs[j].z = v.z * K2; wfs[j].w = v.w * K2;
        float4 wv = *(const float4*)(w1 + (cg << 2) + (j << 5));
        W1S += wv.x + wv.y + wv.z + wv.w;
    }
    __syncthreads();
    float s[5] = {W1S, W1S, W1S, W1S, W1S};
#pragma unroll
    for (int j = 0; j < 16; j++) {
        float4 w14 = *(const float4*)&w1m2[(cg << 2) + (j << 5)];
#pragma unroll
        for (int m = 0; m < 5; m++) {
            float4 wp4 = *(const float4*)&wpL[m][(cg << 2) + (j << 5)];
            s[m] += w14.x * __builtin_amdgcn_rcpf(__builtin_amdgcn_exp2f(wfs[j].x + wp4.x) + 1.f);
            s[m] += w14.y * __builtin_amdgcn_rcpf(__builtin_amdgcn_exp2f(wfs[j].y + wp4.y) + 1.f);
            s[m] += w14.z * __builtin_amdgcn_rcpf(__builtin_amdgcn_exp2f(wfs[j].z + wp4.z) + 1.f);
            s[m] += w14.w * __builtin_amdgcn_rcpf(__builtin_amdgcn_exp2f(wfs[j].w + wp4.w) + 1.f);
        }
    }
#pragma unroll
    for (int m = 0; m < 5; m++) {
        s[m] += __shfl_xor(s[m], 1);
        s[m] += __shfl_xor(s[m], 2);
        s[m] += __shfl_xor(s[m], 4);
    }
    if (cg == 0) {
#pragma unroll
        for (int m = 0; m < 5; m++)
            scores[((size_t)b * ML_ + mg + m) * T_ + t] = s[m];
    }
}

// weighted sum with fused softmax
__global__ __launch_bounds__(256) void wsum_kernel(const float* __restrict__ scores,
                                                   const float* __restrict__ wf,
                                                   float* __restrict__ out) {
    __shared__ float at[T_][8];
    __shared__ float redmax[4][8];
    __shared__ float redsum[4][8];
    int tid = threadIdx.x;
    int lane = tid & 63, wv = tid >> 6;
    int b = blockIdx.y, m0 = blockIdx.x * 5;
    float s[5];
#pragma unroll
    for (int q = 0; q < 5; q++)
        s[q] = scores[((size_t)b * ML_ + m0 + q) * T_ + tid];
#pragma unroll
    for (int q = 0; q < 5; q++) {
        float mx = s[q];
        for (int o = 32; o; o >>= 1) mx = fmaxf(mx, __shfl_xor(mx, o));
        if (lane == 0) redmax[wv][q] = mx;
    }
    __syncthreads();
    float e[5];
#pragma unroll
    for (int q = 0; q < 5; q++) {
        float m = fmaxf(fmaxf(redmax[0][q], redmax[1][q]), fmaxf(redmax[2][q], redmax[3][q]));
        e[q] = __expf(s[q] - m);
        float sm = e[q];
        for (int o = 32; o; o >>= 1) sm += __shfl_xor(sm, o);
        if (lane == 0) redsum[wv][q] = sm;
    }
    __syncthreads();
#pragma unroll
    for (int q = 0; q < 5; q++) {
        float sm = redsum[0][q] + redsum[1][q] + redsum[2][q] + redsum[3][q];
        at[tid][q] = e[q] / sm;
    }
    __syncthreads();
    int c0 = tid << 1;
    const float* wfb = wf + (size_t)b * T_ * D_ + c0;
    float acc[5][2] = {};
    for (int t = 0; t < T_; t++) {
        float2 v = *(const float2*)(wfb + (size_t)t * D_);
        float4 a4 = *(const float4*)&at[t][0];
        float a5 = at[t][4];
        acc[0][0] += a4.x * v.x; acc[0][1] += a4.x * v.y;
        acc[1][0] += a4.y * v.x; acc[1][1] += a4.y * v.y;
        acc[2][0] += a4.z * v.x; acc[2][1] += a4.z * v.y;
        acc[3][0] += a4.w * v.x; acc[3][1] += a4.w * v.y;
        acc[4][0] += a5 * v.x;   acc[4][1] += a5 * v.y;
    }
#pragma unroll
    for (int q = 0; q < 5; q++) {
        float2 o;
        o.x = acc[q][0]; o.y = acc[q][1];
        *(float2*)(out + ((size_t)b * ML_ + m0 + q) * D_ + c0) = o;
    }
}

extern "C" void kernel_launch(void* const* d_in, const int* in_sizes, int n_in,
                              void* d_out, int out_size, void* d_ws, size_t ws_size,
                              hipStream_t stream) {
    (void)in_sizes; (void)n_in; (void)out_size; (void)ws_size;
    const float* x        = (const float*)d_in[0];
    const int*   epos     = (const int*)d_in[1];
    const int*   gpos     = (const int*)d_in[2];
    const float* pos_tab  = (const float*)d_in[3];
    const float* ln1_s    = (const float*)d_in[4];
    const float* ln1_b    = (const float*)d_in[5];
    const float* Wq       = (const float*)d_in[6];
    const float* bq       = (const float*)d_in[7];
    const float* Wk       = (const float*)d_in[8];
    const float* bk       = (const float*)d_in[9];
    const float* Wv       = (const float*)d_in[10];
    const float* bv       = (const float*)d_in[11];
    const float* Wo       = (const float*)d_in[12];
    const float* bo       = (const float*)d_in[13];
    const float* ln2_s    = (const float*)d_in[14];
    const float* ln2_b    = (const float*)d_in[15];
    const float* W1       = (const float*)d_in[16];
    const float* b1       = (const float*)d_in[17];
    const float* W2       = (const float*)d_in[18];
    const float* b2       = (const float*)d_in[19];
    const float* lnf_s    = (const float*)d_in[20];
    const float* lnf_b    = (const float*)d_in[21];
    const float* fc0_w    = (const float*)d_in[22];
    const float* fc0_b    = (const float*)d_in[23];
    const float* emb      = (const float*)d_in[24];
    const float* fc1_w    = (const float*)d_in[25];

    char* ws = (char*)d_ws;
    ushort_t* enc = (ushort_t*)(ws);                    // 8.39 MB (bf16 residual stream)
    ushort_t* hi  = (ushort_t*)(ws + 16777216);         // 8.39 MB
    ushort_t* qb  = (ushort_t*)(ws + 25165824);         // q
    ushort_t* kb  = (ushort_t*)(ws + 33554432);         // k (scb overlay later)
    float*    scb = (float*)(ws + 33554432);
    ushort_t* vt  = (ushort_t*)(ws + 41943040);         // v^T (h1 overlays)
    ushort_t* h1  = (ushort_t*)(ws + 41943040);
    ushort_t* ao  = (ushort_t*)(ws + 50331648);
    float*    wf  = (float*)(ws + 58720256);            // 16.78 MB
    ushort_t* wt  = (ushort_t*)(ws + 75497472);         // 13 slices of 512KB
    const size_t WSL = (size_t)D_ * D_;

    convert_w_kernel<<<13 * 64, 256, 0, stream>>>(Wq, Wk, Wv, Wo, W1, W2, fc0_w, wt);
    prep_kernel<<<dim3(4, 8, 32), 256, 0, stream>>>(x, epos, pos_tab, enc);

    for (int l = 0; l < 2; l++) {
        size_t o1 = (size_t)l * D_;
        const ushort_t* WqkvT = wt + (l * 6 + 0) * WSL;
        const ushort_t* WoT = wt + (l * 6 + 3) * WSL;
        const ushort_t* W1T = wt + (l * 6 + 4) * WSL;
        const ushort_t* W2T = wt + (l * 6 + 5) * WSL;

        ln_kernel<<<2048, 256, 0, stream>>>(enc, ln1_s + o1, ln1_b + o1, hi);
        gemm_qkv_kernel<<<768, 256, 0, stream>>>(hi, WqkvT, bq + o1, bk + o1, bv + o1, qb);
        attn_fused_kernel<<<dim3(4, 256), 256, 0, stream>>>(qb, kb, vt, ao);
        gemm_kernel<2><<<512, 256, 0, stream>>>(ao, WoT, 8, bo + o1, enc, nullptr, enc);
        ln_kernel<<<2048, 256, 0, stream>>>(enc, ln2_s + o1, ln2_b + o1, hi);
        gemm_kernel<3><<<512, 256, 0, stream>>>(hi, W1T, 8, b1 + o1, nullptr, nullptr, h1);
        gemm_kernel<2><<<512, 256, 0, stream>>>(h1, W2T, 8, b2 + o1, enc, nullptr, enc);
    }

    ln_kernel<<<2048, 256, 0, stream>>>(enc, lnf_s, lnf_b, hi);
    gemm_kernel<4><<<512, 256, 0, stream>>>(hi, wt + 12 * WSL, 8, fc0_b, nullptr, wf, nullptr);
    scores_kernel<<<dim3(8, 32, 5), 256, 0, stream>>>(wf, gpos, emb, fc1_w, scb);
    wsum_kernel<<<dim3(5, 32), 256, 0, stream>>>(scb, wf, (float*)d_out);
}